// Round 1
// baseline (917.666 us; speedup 1.0000x reference)
//
#include <hip/hip_runtime.h>
#include <math.h>

#define N_NODES 50000
#define E_EDGES 800000
#define ETOT    850000   // E + N self loops
#define F_INF   512
#define HEADS   8
#define C1      64       // HEADS*HID
#define NCLS    7
#define SLOPE   0.2f

__device__ __forceinline__ unsigned enc_f(float f){
    unsigned u = __float_as_uint(f);
    return (u & 0x80000000u) ? ~u : (u | 0x80000000u);
}
__device__ __forceinline__ float dec_f(unsigned u){
    unsigned b = (u & 0x80000000u) ? (u ^ 0x80000000u) : ~u;
    return __uint_as_float(b);
}
__device__ __forceinline__ float leaky(float x){ return x > 0.f ? x : SLOPE * x; }

// ---------------- init accumulators (ws not re-poisoned between replays) ----
__global__ void k_init(unsigned* m1u, float* d1, float* num1,
                       unsigned* m2u, float* d2, float* num2){
    int i = blockIdx.x * 256 + threadIdx.x;
    int stride = gridDim.x * 256;
    for (int j = i; j < N_NODES * C1;    j += stride) num1[j] = 0.f;
    for (int j = i; j < N_NODES * HEADS; j += stride){ m1u[j] = 0u; d1[j] = 0.f; }
    for (int j = i; j < N_NODES * NCLS;  j += stride) num2[j] = 0.f;
    for (int j = i; j < N_NODES;         j += stride){ m2u[j] = 0u; d2[j] = 0.f; }
}

// ---------------- layer1 GEMM + attention logits ---------------------------
// block = 256 = 4 waves; each wave computes 4 rows x 64 cols. lane = col.
__global__ __launch_bounds__(256) void k_gemm1(
        const float* __restrict__ x, const float* __restrict__ W1,
        const float* __restrict__ a1s, const float* __restrict__ a1d,
        float* __restrict__ h1, float* __restrict__ als1, float* __restrict__ ald1){
    int lane = threadIdx.x & 63;
    int wv   = threadIdx.x >> 6;
    int row0 = blockIdx.x * 16 + wv * 4;
    const float* x0 = x + (size_t)row0 * F_INF;
    float acc0 = 0.f, acc1 = 0.f, acc2 = 0.f, acc3 = 0.f;
    for (int k = 0; k < F_INF; k += 4){
        float4 xa = *(const float4*)(x0 + k);
        float4 xb = *(const float4*)(x0 + F_INF + k);
        float4 xc = *(const float4*)(x0 + 2 * F_INF + k);
        float4 xd = *(const float4*)(x0 + 3 * F_INF + k);
        float w0 = W1[(k + 0) * C1 + lane];
        float w1 = W1[(k + 1) * C1 + lane];
        float w2 = W1[(k + 2) * C1 + lane];
        float w3 = W1[(k + 3) * C1 + lane];
        acc0 = fmaf(xa.x, w0, acc0); acc0 = fmaf(xa.y, w1, acc0);
        acc0 = fmaf(xa.z, w2, acc0); acc0 = fmaf(xa.w, w3, acc0);
        acc1 = fmaf(xb.x, w0, acc1); acc1 = fmaf(xb.y, w1, acc1);
        acc1 = fmaf(xb.z, w2, acc1); acc1 = fmaf(xb.w, w3, acc1);
        acc2 = fmaf(xc.x, w0, acc2); acc2 = fmaf(xc.y, w1, acc2);
        acc2 = fmaf(xc.z, w2, acc2); acc2 = fmaf(xc.w, w3, acc2);
        acc3 = fmaf(xd.x, w0, acc3); acc3 = fmaf(xd.y, w1, acc3);
        acc3 = fmaf(xd.z, w2, acc3); acc3 = fmaf(xd.w, w3, acc3);
    }
    float as = a1s[lane], ad = a1d[lane];
    float accs[4] = {acc0, acc1, acc2, acc3};
    #pragma unroll
    for (int r = 0; r < 4; r++){
        int n = row0 + r;
        h1[(size_t)n * C1 + lane] = accs[r];
        float ps = accs[r] * as;
        float pd = accs[r] * ad;
        ps += __shfl_xor(ps, 1); ps += __shfl_xor(ps, 2); ps += __shfl_xor(ps, 4);
        pd += __shfl_xor(pd, 1); pd += __shfl_xor(pd, 2); pd += __shfl_xor(pd, 4);
        if ((lane & 7) == 0){
            als1[n * HEADS + (lane >> 3)] = ps;
            ald1[n * HEADS + (lane >> 3)] = pd;
        }
    }
}

// ---------------- layer1 edge pass A: segment max --------------------------
__global__ void k_edgeA1(const int* __restrict__ ei, const float* __restrict__ als1,
                         const float* __restrict__ ald1, unsigned* __restrict__ m1u){
    int e = blockIdx.x * 256 + threadIdx.x;
    if (e >= ETOT) return;
    int s, d;
    if (e < E_EDGES){ s = ei[e]; d = ei[E_EDGES + e]; } else { s = d = e - E_EDGES; }
    #pragma unroll
    for (int h = 0; h < HEADS; h++){
        float v = leaky(als1[s * HEADS + h] + ald1[d * HEADS + h]);
        atomicMax(&m1u[d * HEADS + h], enc_f(v));
    }
}

// ---------------- layer1 edge pass B: exp + scatter-add --------------------
// one wave per edge; lane = feature (0..63), head = lane>>3
__global__ __launch_bounds__(256) void k_edgeB1(
        const int* __restrict__ ei, const float* __restrict__ als1,
        const float* __restrict__ ald1, const unsigned* __restrict__ m1u,
        const float* __restrict__ h1, float* __restrict__ d1, float* __restrict__ num1){
    int lane = threadIdx.x & 63;
    int e = blockIdx.x * 4 + (threadIdx.x >> 6);   // grid sized exactly
    int s, d;
    if (e < E_EDGES){ s = ei[e]; d = ei[E_EDGES + e]; } else { s = d = e - E_EDGES; }
    int h = lane >> 3;
    float v  = leaky(als1[s * HEADS + h] + ald1[d * HEADS + h]);
    float m  = dec_f(m1u[d * HEADS + h]);
    float ex = expf(v - m);
    if ((lane & 7) == 0) atomicAdd(&d1[d * HEADS + h], ex);
    atomicAdd(&num1[(size_t)d * C1 + lane], ex * h1[(size_t)s * C1 + lane]);
}

// ---------------- node pass: normalize + ELU + layer2 GEMM + logits --------
__global__ __launch_bounds__(256) void k_node1(
        const float* __restrict__ num1, const float* __restrict__ d1,
        const float* __restrict__ b1, const float* __restrict__ W2,
        const float* __restrict__ a2s, const float* __restrict__ a2d,
        float* __restrict__ h2, float* __restrict__ als2, float* __restrict__ ald2){
    __shared__ float sh[4][C1];
    int lane = threadIdx.x & 63;
    int wv   = threadIdx.x >> 6;
    int n = blockIdx.x * 4 + wv;
    float den = d1[n * HEADS + (lane >> 3)] + 1e-16f;
    float v = num1[(size_t)n * C1 + lane] / den + b1[lane];
    float el = v > 0.f ? v : expm1f(v);
    sh[wv][lane] = el;
    __syncthreads();
    float hc = 0.f;
    if (lane < NCLS){
        #pragma unroll
        for (int k = 0; k < C1; k++) hc = fmaf(sh[wv][k], W2[k * NCLS + lane], hc);
        h2[n * NCLS + lane] = hc;
    }
    float ps = (lane < NCLS) ? hc * a2s[lane] : 0.f;
    float pd = (lane < NCLS) ? hc * a2d[lane] : 0.f;
    ps += __shfl_xor(ps, 1); ps += __shfl_xor(ps, 2); ps += __shfl_xor(ps, 4);
    pd += __shfl_xor(pd, 1); pd += __shfl_xor(pd, 2); pd += __shfl_xor(pd, 4);
    if (lane == 0){ als2[n] = ps; ald2[n] = pd; }
}

// ---------------- layer2 edge pass A: segment max --------------------------
__global__ void k_edgeA2(const int* __restrict__ ei, const float* __restrict__ als2,
                         const float* __restrict__ ald2, unsigned* __restrict__ m2u){
    int e = blockIdx.x * 256 + threadIdx.x;
    if (e >= ETOT) return;
    int s, d;
    if (e < E_EDGES){ s = ei[e]; d = ei[E_EDGES + e]; } else { s = d = e - E_EDGES; }
    float v = leaky(als2[s] + ald2[d]);
    atomicMax(&m2u[d], enc_f(v));
}

// ---------------- layer2 edge pass B: exp + scatter-add --------------------
// 8 threads per edge: c = 0..6 features, c == 7 handles denominator
__global__ void k_edgeB2(const int* __restrict__ ei, const float* __restrict__ als2,
                         const float* __restrict__ ald2, const unsigned* __restrict__ m2u,
                         const float* __restrict__ h2, float* __restrict__ d2,
                         float* __restrict__ num2){
    int t = blockIdx.x * 256 + threadIdx.x;
    if (t >= ETOT * 8) return;
    int e = t >> 3, c = t & 7;
    int s, d;
    if (e < E_EDGES){ s = ei[e]; d = ei[E_EDGES + e]; } else { s = d = e - E_EDGES; }
    float ex = expf(leaky(als2[s] + ald2[d]) - dec_f(m2u[d]));
    if (c < NCLS) atomicAdd(&num2[d * NCLS + c], ex * h2[s * NCLS + c]);
    else          atomicAdd(&d2[d], ex);
}

// ---------------- final: normalize + log_softmax ---------------------------
__global__ void k_final(const float* __restrict__ num2, const float* __restrict__ d2,
                        const float* __restrict__ b2, float* __restrict__ out){
    int n = blockIdx.x * 256 + threadIdx.x;
    if (n >= N_NODES) return;
    float den = d2[n] + 1e-16f;
    float v[NCLS];
    float mx = -INFINITY;
    #pragma unroll
    for (int c = 0; c < NCLS; c++){
        v[c] = num2[n * NCLS + c] / den + b2[c];
        mx = fmaxf(mx, v[c]);
    }
    float ssum = 0.f;
    #pragma unroll
    for (int c = 0; c < NCLS; c++) ssum += expf(v[c] - mx);
    float lse = mx + logf(ssum);
    #pragma unroll
    for (int c = 0; c < NCLS; c++) out[n * NCLS + c] = v[c] - lse;
}

extern "C" void kernel_launch(void* const* d_in, const int* in_sizes, int n_in,
                              void* d_out, int out_size, void* d_ws, size_t ws_size,
                              hipStream_t stream){
    const float* x    = (const float*)d_in[0];
    const int*   ei   = (const int*)  d_in[1];
    const float* W1   = (const float*)d_in[2];
    const float* a1s  = (const float*)d_in[3];
    const float* a1d  = (const float*)d_in[4];
    const float* b1   = (const float*)d_in[5];
    const float* W2   = (const float*)d_in[6];
    const float* a2s  = (const float*)d_in[7];
    const float* a2d  = (const float*)d_in[8];
    const float* b2   = (const float*)d_in[9];
    float* out = (float*)d_out;

    float* w = (float*)d_ws;
    float*    h1   = w;              w += (size_t)N_NODES * C1;
    float*    als1 = w;              w += N_NODES * HEADS;
    float*    ald1 = w;              w += N_NODES * HEADS;
    unsigned* m1u  = (unsigned*)w;   w += N_NODES * HEADS;
    float*    d1   = w;              w += N_NODES * HEADS;
    float*    num1 = w;              w += (size_t)N_NODES * C1;
    float*    h2   = w;              w += N_NODES * NCLS;
    float*    als2 = w;              w += N_NODES;
    float*    ald2 = w;              w += N_NODES;
    unsigned* m2u  = (unsigned*)w;   w += N_NODES;
    float*    d2   = w;              w += N_NODES;
    float*    num2 = w;              w += N_NODES * NCLS;

    k_init  <<<2048, 256, 0, stream>>>(m1u, d1, num1, m2u, d2, num2);
    k_gemm1 <<<N_NODES / 16, 256, 0, stream>>>(x, W1, a1s, a1d, h1, als1, ald1);
    k_edgeA1<<<(ETOT + 255) / 256, 256, 0, stream>>>(ei, als1, ald1, m1u);
    k_edgeB1<<<ETOT / 4, 256, 0, stream>>>(ei, als1, ald1, m1u, h1, d1, num1);
    k_node1 <<<N_NODES / 4, 256, 0, stream>>>(num1, d1, b1, W2, a2s, a2d, h2, als2, ald2);
    k_edgeA2<<<(ETOT + 255) / 256, 256, 0, stream>>>(ei, als2, ald2, m2u);
    k_edgeB2<<<(ETOT * 8 + 255) / 256, 256, 0, stream>>>(ei, als2, ald2, m2u, h2, d2, num2);
    k_final <<<(N_NODES + 255) / 256, 256, 0, stream>>>(num2, d2, b2, out);
}

// Round 2
// 597.291 us; speedup vs baseline: 1.5364x; 1.5364x over previous
//
#include <hip/hip_runtime.h>
#include <math.h>

#define N_NODES 50000
#define E_EDGES 800000
#define ETOT    850000   // E + N self loops
#define F_INF   512
#define HEADS   8
#define C1      64       // HEADS*HID
#define NCLS    7
#define SLOPE   0.2f

__device__ __forceinline__ float leaky(float x){ return x > 0.f ? x : SLOPE * x; }

// ---------------- init accumulators (ws not re-poisoned between replays) ----
__global__ void k_init(float* d1, float* num1, float* d2, float* num2){
    int i = blockIdx.x * 256 + threadIdx.x;
    int stride = gridDim.x * 256;
    for (int j = i; j < N_NODES * C1;    j += stride) num1[j] = 0.f;
    for (int j = i; j < N_NODES * HEADS; j += stride) d1[j] = 0.f;
    for (int j = i; j < N_NODES * NCLS;  j += stride) num2[j] = 0.f;
    for (int j = i; j < N_NODES;         j += stride) d2[j] = 0.f;
}

// ---------------- layer1 GEMM + attention logits ---------------------------
// block = 256 = 4 waves; 8 rows/wave (32 rows/block). lane = output col.
// W1 staged in LDS 64x64-f32 chunks, double-buffered, via global_load_lds.
__device__ __forceinline__ void stage_w1(const float* __restrict__ W1, int k0,
                                         float* shbuf, int wv, int lane){
    // chunk = W1[k0:k0+64][0:64], 16 KB, linear copy. wave wv covers 4 KB.
    const float* src = W1 + (size_t)k0 * C1 + wv * 1024 + lane * 4;
    float* dst = shbuf + wv * 1024;
    #pragma unroll
    for (int i = 0; i < 4; i++){
        __builtin_amdgcn_global_load_lds(
            (const __attribute__((address_space(1))) void*)(src + i * 256),
            (__attribute__((address_space(3))) void*)(dst + i * 256),
            16, 0, 0);
    }
}

__global__ __launch_bounds__(256) void k_gemm1(
        const float* __restrict__ x, const float* __restrict__ W1,
        const float* __restrict__ a1s, const float* __restrict__ a1d,
        float* __restrict__ h1, float* __restrict__ als1, float* __restrict__ ald1){
    __shared__ float shw[2][64 * 64];
    int lane = threadIdx.x & 63;
    int wv   = threadIdx.x >> 6;
    int row0 = blockIdx.x * 32 + wv * 8;

    const float* xr[8];
    #pragma unroll
    for (int r = 0; r < 8; r++){
        int n = row0 + r; if (n >= N_NODES) n = N_NODES - 1;   // clamp OOB loads
        xr[r] = x + (size_t)n * F_INF;
    }
    float acc[8];
    #pragma unroll
    for (int r = 0; r < 8; r++) acc[r] = 0.f;

    stage_w1(W1, 0, shw[0], wv, lane);
    __syncthreads();

    for (int c = 0; c < 8; c++){
        int buf = c & 1;
        if (c < 7) stage_w1(W1, (c + 1) * 64, shw[buf ^ 1], wv, lane);
        int k0 = c * 64;
        #pragma unroll 4
        for (int kk = 0; kk < 64; kk += 4){
            float4 xv[8];
            #pragma unroll
            for (int r = 0; r < 8; r++)
                xv[r] = *(const float4*)(xr[r] + k0 + kk);
            float w0 = shw[buf][(kk + 0) * 64 + lane];
            float w1 = shw[buf][(kk + 1) * 64 + lane];
            float w2 = shw[buf][(kk + 2) * 64 + lane];
            float w3 = shw[buf][(kk + 3) * 64 + lane];
            #pragma unroll
            for (int r = 0; r < 8; r++){
                acc[r] = fmaf(xv[r].x, w0, acc[r]);
                acc[r] = fmaf(xv[r].y, w1, acc[r]);
                acc[r] = fmaf(xv[r].z, w2, acc[r]);
                acc[r] = fmaf(xv[r].w, w3, acc[r]);
            }
        }
        __syncthreads();   // staging of c+1 complete; all waves done with buf
    }

    float as = a1s[lane], ad = a1d[lane];
    #pragma unroll
    for (int r = 0; r < 8; r++){
        int n = row0 + r;
        if (n >= N_NODES) break;
        h1[(size_t)n * C1 + lane] = acc[r];
        float ps = acc[r] * as;
        float pd = acc[r] * ad;
        ps += __shfl_xor(ps, 1); ps += __shfl_xor(ps, 2); ps += __shfl_xor(ps, 4);
        pd += __shfl_xor(pd, 1); pd += __shfl_xor(pd, 2); pd += __shfl_xor(pd, 4);
        if ((lane & 7) == 0){
            als1[n * HEADS + (lane >> 3)] = ps;
            ald1[n * HEADS + (lane >> 3)] = pd;
        }
    }
}

// ---------------- layer1 edge pass: exp + scatter-add (no max needed) ------
// one wave per edge; lane = feature (0..63), head = lane>>3
__global__ __launch_bounds__(256) void k_edgeB1(
        const int* __restrict__ ei, const float* __restrict__ als1,
        const float* __restrict__ ald1,
        const float* __restrict__ h1, float* __restrict__ d1, float* __restrict__ num1){
    int lane = threadIdx.x & 63;
    int e = blockIdx.x * 4 + (threadIdx.x >> 6);   // grid sized exactly
    int s, d;
    if (e < E_EDGES){ s = ei[e]; d = ei[E_EDGES + e]; } else { s = d = e - E_EDGES; }
    int h = lane >> 3;
    float v  = leaky(als1[s * HEADS + h] + ald1[d * HEADS + h]);
    float ex = expf(v);
    if ((lane & 7) == 0) atomicAdd(&d1[d * HEADS + h], ex);
    atomicAdd(&num1[(size_t)d * C1 + lane], ex * h1[(size_t)s * C1 + lane]);
}

// ---------------- node pass: normalize + ELU + layer2 GEMM + logits --------
__global__ __launch_bounds__(256) void k_node1(
        const float* __restrict__ num1, const float* __restrict__ d1,
        const float* __restrict__ b1, const float* __restrict__ W2,
        const float* __restrict__ a2s, const float* __restrict__ a2d,
        float* __restrict__ h2, float* __restrict__ als2, float* __restrict__ ald2){
    __shared__ float sh[4][C1];
    int lane = threadIdx.x & 63;
    int wv   = threadIdx.x >> 6;
    int n = blockIdx.x * 4 + wv;
    float den = d1[n * HEADS + (lane >> 3)] + 1e-16f;
    float v = num1[(size_t)n * C1 + lane] / den + b1[lane];
    float el = v > 0.f ? v : expm1f(v);
    sh[wv][lane] = el;
    __syncthreads();
    float hc = 0.f;
    if (lane < NCLS){
        #pragma unroll
        for (int k = 0; k < C1; k++) hc = fmaf(sh[wv][k], W2[k * NCLS + lane], hc);
        h2[n * NCLS + lane] = hc;
    }
    float ps = (lane < NCLS) ? hc * a2s[lane] : 0.f;
    float pd = (lane < NCLS) ? hc * a2d[lane] : 0.f;
    ps += __shfl_xor(ps, 1); ps += __shfl_xor(ps, 2); ps += __shfl_xor(ps, 4);
    pd += __shfl_xor(pd, 1); pd += __shfl_xor(pd, 2); pd += __shfl_xor(pd, 4);
    if (lane == 0){ als2[n] = ps; ald2[n] = pd; }
}

// ---------------- layer2 edge pass: exp + scatter-add ----------------------
// 8 threads per edge: c = 0..6 features, c == 7 handles denominator
__global__ void k_edgeB2(const int* __restrict__ ei, const float* __restrict__ als2,
                         const float* __restrict__ ald2,
                         const float* __restrict__ h2, float* __restrict__ d2,
                         float* __restrict__ num2){
    int t = blockIdx.x * 256 + threadIdx.x;
    if (t >= ETOT * 8) return;
    int e = t >> 3, c = t & 7;
    int s, d;
    if (e < E_EDGES){ s = ei[e]; d = ei[E_EDGES + e]; } else { s = d = e - E_EDGES; }
    float ex = expf(leaky(als2[s] + ald2[d]));
    if (c < NCLS) atomicAdd(&num2[d * NCLS + c], ex * h2[s * NCLS + c]);
    else          atomicAdd(&d2[d], ex);
}

// ---------------- final: normalize + log_softmax ---------------------------
__global__ void k_final(const float* __restrict__ num2, const float* __restrict__ d2,
                        const float* __restrict__ b2, float* __restrict__ out){
    int n = blockIdx.x * 256 + threadIdx.x;
    if (n >= N_NODES) return;
    float den = d2[n] + 1e-16f;
    float v[NCLS];
    float mx = -INFINITY;
    #pragma unroll
    for (int c = 0; c < NCLS; c++){
        v[c] = num2[n * NCLS + c] / den + b2[c];
        mx = fmaxf(mx, v[c]);
    }
    float ssum = 0.f;
    #pragma unroll
    for (int c = 0; c < NCLS; c++) ssum += expf(v[c] - mx);
    float lse = mx + logf(ssum);
    #pragma unroll
    for (int c = 0; c < NCLS; c++) out[n * NCLS + c] = v[c] - lse;
}

extern "C" void kernel_launch(void* const* d_in, const int* in_sizes, int n_in,
                              void* d_out, int out_size, void* d_ws, size_t ws_size,
                              hipStream_t stream){
    const float* x    = (const float*)d_in[0];
    const int*   ei   = (const int*)  d_in[1];
    const float* W1   = (const float*)d_in[2];
    const float* a1s  = (const float*)d_in[3];
    const float* a1d  = (const float*)d_in[4];
    const float* b1   = (const float*)d_in[5];
    const float* W2   = (const float*)d_in[6];
    const float* a2s  = (const float*)d_in[7];
    const float* a2d  = (const float*)d_in[8];
    const float* b2   = (const float*)d_in[9];
    float* out = (float*)d_out;

    float* w = (float*)d_ws;
    float*    h1   = w;              w += (size_t)N_NODES * C1;
    float*    als1 = w;              w += N_NODES * HEADS;
    float*    ald1 = w;              w += N_NODES * HEADS;
    float*    d1   = w;              w += N_NODES * HEADS;
    float*    num1 = w;              w += (size_t)N_NODES * C1;
    float*    h2   = w;              w += N_NODES * NCLS;
    float*    als2 = w;              w += N_NODES;
    float*    ald2 = w;              w += N_NODES;
    float*    d2   = w;              w += N_NODES;
    float*    num2 = w;              w += N_NODES * NCLS;

    k_init  <<<1024, 256, 0, stream>>>(d1, num1, d2, num2);
    k_gemm1 <<<(N_NODES + 31) / 32, 256, 0, stream>>>(x, W1, a1s, a1d, h1, als1, ald1);
    k_edgeB1<<<ETOT / 4, 256, 0, stream>>>(ei, als1, ald1, h1, d1, num1);
    k_node1 <<<N_NODES / 4, 256, 0, stream>>>(num1, d1, b1, W2, a2s, a2d, h2, als2, ald2);
    k_edgeB2<<<(ETOT * 8 + 255) / 256, 256, 0, stream>>>(ei, als2, ald2, h2, d2, num2);
    k_final <<<(N_NODES + 255) / 256, 256, 0, stream>>>(num2, d2, b2, out);
}

// Round 4
// 420.700 us; speedup vs baseline: 2.1813x; 1.4198x over previous
//
#include <hip/hip_runtime.h>
#include <math.h>

#define N_NODES 50000
#define E_EDGES 800000
#define ETOT    850000   // E + N self loops
#define F_INF   512
#define HEADS   8
#define C1      64       // HEADS*HID
#define NCLS    7
#define SLOPE   0.2f

typedef __attribute__((ext_vector_type(8))) short short8;
typedef __attribute__((ext_vector_type(4))) float f32x4;

__device__ __forceinline__ float leaky(float x){ return x > 0.f ? x : SLOPE * x; }

// split f32 -> bf16 hi (truncated) + bf16 lo (RNE of residual)
__device__ __forceinline__ void split1(float v, short& h, short& l){
    unsigned u = __float_as_uint(v);
    unsigned hw = u >> 16;
    float fh = __uint_as_float(hw << 16);
    float r  = v - fh;
    unsigned ul = __float_as_uint(r);
    unsigned lw = (ul + 0x7fffu + ((ul >> 16) & 1u)) >> 16;
    h = (short)hw; l = (short)lw;
}

// ---------------- init accumulators (ws not re-poisoned between replays) ----
__global__ void k_init(float* d1, float* num1, float* d2, float* num2){
    int i = blockIdx.x * 256 + threadIdx.x;
    int stride = gridDim.x * 256;
    for (int j = i; j < N_NODES * C1;    j += stride) num1[j] = 0.f;
    for (int j = i; j < N_NODES * HEADS; j += stride) d1[j] = 0.f;
    for (int j = i; j < N_NODES * NCLS;  j += stride) num2[j] = 0.f;
    for (int j = i; j < N_NODES;         j += stride) d2[j] = 0.f;
}

// ---------------- pack W1 into per-lane MFMA B-fragments (hi/lo bf16) ------
// layout: wf[ks][nt][lane][j], ks=0..15 (K32 steps), nt=0..3 (N16 tiles)
__global__ void k_wprep(const float* __restrict__ W1,
                        unsigned short* __restrict__ wfh,
                        unsigned short* __restrict__ wfl){
    int t = blockIdx.x * 256 + threadIdx.x;      // 4096 threads
    int lane = t & 63, nt = (t >> 6) & 3, ks = t >> 8;
    int c  = nt * 16 + (lane & 15);
    int k0 = ks * 32 + (lane >> 4) * 8;
    size_t base = ((size_t)(ks * 4 + nt) * 64 + lane) * 8;
    #pragma unroll
    for (int j = 0; j < 8; j++){
        short h, l;
        split1(W1[(size_t)(k0 + j) * C1 + c], h, l);
        wfh[base + j] = (unsigned short)h;
        wfl[base + j] = (unsigned short)l;
    }
}

// ---------------- layer1 GEMM via split-bf16 MFMA --------------------------
// block = 256 = 4 waves; wave computes 16 rows x 64 cols. Grid covers M.
__global__ __launch_bounds__(256) void k_gemm1(
        const float* __restrict__ x,
        const unsigned short* __restrict__ wfh,
        const unsigned short* __restrict__ wfl,
        float* __restrict__ h1){
    int lane = threadIdx.x & 63;
    int wv   = threadIdx.x >> 6;
    int row0 = blockIdx.x * 64 + wv * 16;

    int arow = row0 + (lane & 15);
    if (arow >= N_NODES) arow = N_NODES - 1;     // clamp (stores guarded)
    const float* xp = x + (size_t)arow * F_INF + (lane >> 4) * 8;

    f32x4 acc[4];
    #pragma unroll
    for (int nt = 0; nt < 4; nt++) acc[nt] = (f32x4){0.f, 0.f, 0.f, 0.f};

    for (int ks = 0; ks < 16; ks++){
        float4 va = *(const float4*)(xp + ks * 32);
        float4 vb = *(const float4*)(xp + ks * 32 + 4);
        short8 ah, al;
        {
            float v[8] = {va.x, va.y, va.z, va.w, vb.x, vb.y, vb.z, vb.w};
            #pragma unroll
            for (int j = 0; j < 8; j++){ short h, l; split1(v[j], h, l); ah[j] = h; al[j] = l; }
        }
        const unsigned short* bh0 = wfh + ((size_t)(ks * 4) * 64 + lane) * 8;
        const unsigned short* bl0 = wfl + ((size_t)(ks * 4) * 64 + lane) * 8;
        #pragma unroll
        for (int nt = 0; nt < 4; nt++){
            short8 bh = *(const short8*)(bh0 + (size_t)nt * 64 * 8);
            short8 bl = *(const short8*)(bl0 + (size_t)nt * 64 * 8);
            acc[nt] = __builtin_amdgcn_mfma_f32_16x16x32_bf16(ah, bh, acc[nt], 0, 0, 0);
            acc[nt] = __builtin_amdgcn_mfma_f32_16x16x32_bf16(ah, bl, acc[nt], 0, 0, 0);
            acc[nt] = __builtin_amdgcn_mfma_f32_16x16x32_bf16(al, bh, acc[nt], 0, 0, 0);
        }
    }

    // C/D layout: col = lane&15, row = (lane>>4)*4 + reg   [m89-verified]
    int g = lane >> 4, c = lane & 15;
    #pragma unroll
    for (int nt = 0; nt < 4; nt++){
        #pragma unroll
        for (int r = 0; r < 4; r++){
            int row = row0 + g * 4 + r;
            if (row < N_NODES) h1[(size_t)row * C1 + nt * 16 + c] = acc[nt][r];
        }
    }
}

// ---------------- attention logits from h1 ---------------------------------
// thread = (node, head): als[n][h] = dot(h1[n][h*8..], a1s[h*8..])
__global__ void k_logits(const float* __restrict__ h1, const float* __restrict__ a1s,
                         const float* __restrict__ a1d,
                         float* __restrict__ als1, float* __restrict__ ald1){
    int t = blockIdx.x * 256 + threadIdx.x;
    if (t >= N_NODES * HEADS) return;
    int h = t & 7;
    const float* hp = h1 + (size_t)t * 8;
    float4 p = *(const float4*)(hp);
    float4 q = *(const float4*)(hp + 4);
    const float* as = a1s + h * 8;
    const float* ad = a1d + h * 8;
    float s = p.x*as[0] + p.y*as[1] + p.z*as[2] + p.w*as[3]
            + q.x*as[4] + q.y*as[5] + q.z*as[6] + q.w*as[7];
    float d = p.x*ad[0] + p.y*ad[1] + p.z*ad[2] + p.w*ad[3]
            + q.x*ad[4] + q.y*ad[5] + q.z*ad[6] + q.w*ad[7];
    als1[t] = s; ald1[t] = d;
}

// ---------------- layer1 edge pass: exp + scatter-add ----------------------
// one wave per edge; lane = feature (0..63), head = lane>>3
__global__ __launch_bounds__(256) void k_edgeB1(
        const int* __restrict__ ei, const float* __restrict__ als1,
        const float* __restrict__ ald1,
        const float* __restrict__ h1, float* __restrict__ d1, float* __restrict__ num1){
    int lane = threadIdx.x & 63;
    int e = blockIdx.x * 4 + (threadIdx.x >> 6);   // grid sized exactly
    int s, d;
    if (e < E_EDGES){ s = ei[e]; d = ei[E_EDGES + e]; } else { s = d = e - E_EDGES; }
    int h = lane >> 3;
    float v  = leaky(als1[s * HEADS + h] + ald1[d * HEADS + h]);
    float ex = expf(v);
    if ((lane & 7) == 0) atomicAdd(&d1[d * HEADS + h], ex);
    atomicAdd(&num1[(size_t)d * C1 + lane], ex * h1[(size_t)s * C1 + lane]);
}

// ---------------- node pass: normalize + ELU + layer2 GEMM + logits --------
__global__ __launch_bounds__(256) void k_node1(
        const float* __restrict__ num1, const float* __restrict__ d1,
        const float* __restrict__ b1, const float* __restrict__ W2,
        const float* __restrict__ a2s, const float* __restrict__ a2d,
        float* __restrict__ h2, float* __restrict__ als2, float* __restrict__ ald2){
    __shared__ float sh[4][C1];
    int lane = threadIdx.x & 63;
    int wv   = threadIdx.x >> 6;
    int n = blockIdx.x * 4 + wv;
    float den = d1[n * HEADS + (lane >> 3)] + 1e-16f;
    float v = num1[(size_t)n * C1 + lane] / den + b1[lane];
    float el = v > 0.f ? v : expm1f(v);
    sh[wv][lane] = el;
    __syncthreads();
    float hc = 0.f;
    if (lane < NCLS){
        #pragma unroll
        for (int k = 0; k < C1; k++) hc = fmaf(sh[wv][k], W2[k * NCLS + lane], hc);
        h2[n * NCLS + lane] = hc;
    }
    float ps = (lane < NCLS) ? hc * a2s[lane] : 0.f;
    float pd = (lane < NCLS) ? hc * a2d[lane] : 0.f;
    ps += __shfl_xor(ps, 1); ps += __shfl_xor(ps, 2); ps += __shfl_xor(ps, 4);
    pd += __shfl_xor(pd, 1); pd += __shfl_xor(pd, 2); pd += __shfl_xor(pd, 4);
    if (lane == 0){ als2[n] = ps; ald2[n] = pd; }
}

// ---------------- layer2 edge pass: exp + scatter-add ----------------------
__global__ void k_edgeB2(const int* __restrict__ ei, const float* __restrict__ als2,
                         const float* __restrict__ ald2,
                         const float* __restrict__ h2, float* __restrict__ d2,
                         float* __restrict__ num2){
    int t = blockIdx.x * 256 + threadIdx.x;
    if (t >= ETOT * 8) return;
    int e = t >> 3, c = t & 7;
    int s, d;
    if (e < E_EDGES){ s = ei[e]; d = ei[E_EDGES + e]; } else { s = d = e - E_EDGES; }
    float ex = expf(leaky(als2[s] + ald2[d]));
    if (c < NCLS) atomicAdd(&num2[d * NCLS + c], ex * h2[s * NCLS + c]);
    else          atomicAdd(&d2[d], ex);
}

// ---------------- final: normalize + log_softmax ---------------------------
__global__ void k_final(const float* __restrict__ num2, const float* __restrict__ d2,
                        const float* __restrict__ b2, float* __restrict__ out){
    int n = blockIdx.x * 256 + threadIdx.x;
    if (n >= N_NODES) return;
    float den = d2[n] + 1e-16f;
    float v[NCLS];
    float mx = -INFINITY;
    #pragma unroll
    for (int c = 0; c < NCLS; c++){
        v[c] = num2[n * NCLS + c] / den + b2[c];
        mx = fmaxf(mx, v[c]);
    }
    float ssum = 0.f;
    #pragma unroll
    for (int c = 0; c < NCLS; c++) ssum += expf(v[c] - mx);
    float lse = mx + logf(ssum);
    #pragma unroll
    for (int c = 0; c < NCLS; c++) out[n * NCLS + c] = v[c] - lse;
}

extern "C" void kernel_launch(void* const* d_in, const int* in_sizes, int n_in,
                              void* d_out, int out_size, void* d_ws, size_t ws_size,
                              hipStream_t stream){
    const float* x    = (const float*)d_in[0];
    const int*   ei   = (const int*)  d_in[1];
    const float* W1   = (const float*)d_in[2];
    const float* a1s  = (const float*)d_in[3];
    const float* a1d  = (const float*)d_in[4];
    const float* b1   = (const float*)d_in[5];
    const float* W2   = (const float*)d_in[6];
    const float* a2s  = (const float*)d_in[7];
    const float* a2d  = (const float*)d_in[8];
    const float* b2   = (const float*)d_in[9];
    float* out = (float*)d_out;

    float* w = (float*)d_ws;
    float*    h1   = w;              w += (size_t)N_NODES * C1;
    float*    als1 = w;              w += N_NODES * HEADS;
    float*    ald1 = w;              w += N_NODES * HEADS;
    float*    d1   = w;              w += N_NODES * HEADS;
    float*    num1 = w;              w += (size_t)N_NODES * C1;
    float*    h2   = w;              w += N_NODES * NCLS;
    float*    als2 = w;              w += N_NODES;
    float*    ald2 = w;              w += N_NODES;
    float*    d2   = w;              w += N_NODES;
    float*    num2 = w;              w += N_NODES * NCLS;
    unsigned short* wfh = (unsigned short*)w;  w += (16 * 4 * 64 * 8) / 2;
    unsigned short* wfl = (unsigned short*)w;  w += (16 * 4 * 64 * 8) / 2;

    k_init  <<<1024, 256, 0, stream>>>(d1, num1, d2, num2);
    k_wprep <<<16, 256, 0, stream>>>(W1, wfh, wfl);
    k_gemm1 <<<(N_NODES + 63) / 64, 256, 0, stream>>>(x, wfh, wfl, h1);
    k_logits<<<(N_NODES * HEADS + 255) / 256, 256, 0, stream>>>(h1, a1s, a1d, als1, ald1);
    k_edgeB1<<<ETOT / 4, 256, 0, stream>>>(ei, als1, ald1, h1, d1, num1);
    k_node1 <<<N_NODES / 4, 256, 0, stream>>>(num1, d1, b1, W2, a2s, a2d, h2, als2, ald2);
    k_edgeB2<<<(ETOT * 8 + 255) / 256, 256, 0, stream>>>(ei, als2, ald2, h2, d2, num2);
    k_final <<<(N_NODES + 255) / 256, 256, 0, stream>>>(num2, d2, b2, out);
}

// Round 7
// 377.425 us; speedup vs baseline: 2.4314x; 1.1147x over previous
//
#include <hip/hip_runtime.h>
#include <math.h>

#define N_NODES 50000
#define E_EDGES 800000
#define ETOT    850000   // E + N self loops
#define F_INF   512
#define HEADS   8
#define C1      64       // HEADS*HID
#define NCLS    7
#define SLOPE   0.2f

typedef __attribute__((ext_vector_type(8))) short short8;
typedef __attribute__((ext_vector_type(4))) float f32x4;

__device__ __forceinline__ float leaky(float x){ return x > 0.f ? x : SLOPE * x; }

// split f32 -> bf16 hi (truncated) + bf16 lo (RNE of residual)
__device__ __forceinline__ void split1(float v, short& h, short& l){
    unsigned u = __float_as_uint(v);
    unsigned hw = u >> 16;
    float fh = __uint_as_float(hw << 16);
    float r  = v - fh;
    unsigned ul = __float_as_uint(r);
    unsigned lw = (ul + 0x7fffu + ((ul >> 16) & 1u)) >> 16;
    h = (short)hw; l = (short)lw;
}

// ================= CSR build =================
// deg starts at 1 (self loop); cur zeroed in k_scan.
__global__ void k_zero(int* deg){
    int n = blockIdx.x * 256 + threadIdx.x;
    if (n < N_NODES) deg[n] = 1;
}

__global__ void k_hist(const int* __restrict__ ei, int* __restrict__ deg){
    int e = blockIdx.x * 256 + threadIdx.x;
    if (e < E_EDGES) atomicAdd(&deg[ei[E_EDGES + e]], 1);
}

#define SCAN_T 1024
#define CHUNK  ((N_NODES + SCAN_T - 1) / SCAN_T)   // 49
__global__ __launch_bounds__(SCAN_T) void k_scan(const int* __restrict__ deg,
                                                 int* __restrict__ ofs,
                                                 int* __restrict__ cur,
                                                 int* __restrict__ csr_src){
    __shared__ int sp[SCAN_T];
    int t = threadIdx.x;
    int lo = t * CHUNK, hi = lo + CHUNK; if (hi > N_NODES) hi = N_NODES;
    int sum = 0;
    for (int i = lo; i < hi; i++) sum += deg[i];
    sp[t] = sum;
    __syncthreads();
    for (int d = 1; d < SCAN_T; d <<= 1){
        int v = (t >= d) ? sp[t - d] : 0;
        __syncthreads();
        sp[t] += v;
        __syncthreads();
    }
    int running = (t > 0) ? sp[t - 1] : 0;   // exclusive base for this chunk
    for (int i = lo; i < hi; i++){
        ofs[i] = running;
        cur[i] = 0;
        int dg = deg[i];
        csr_src[running + dg - 1] = i;       // self-loop in last slot
        running += dg;
    }
}

__global__ void k_scatter(const int* __restrict__ ei, const int* __restrict__ ofs,
                          int* __restrict__ cur, int* __restrict__ csr_src){
    int e = blockIdx.x * 256 + threadIdx.x;
    if (e >= E_EDGES) return;
    int d = ei[E_EDGES + e];
    int p = atomicAdd(&cur[d], 1);
    csr_src[ofs[d] + p] = ei[e];
}

// ================= layer 1 GEMM (split-bf16 MFMA) =================
__global__ void k_wprep(const float* __restrict__ W1,
                        unsigned short* __restrict__ wfh,
                        unsigned short* __restrict__ wfl){
    int t = blockIdx.x * 256 + threadIdx.x;      // 4096 threads
    int lane = t & 63, nt = (t >> 6) & 3, ks = t >> 8;
    int c  = nt * 16 + (lane & 15);
    int k0 = ks * 32 + (lane >> 4) * 8;
    size_t base = ((size_t)(ks * 4 + nt) * 64 + lane) * 8;
    #pragma unroll
    for (int j = 0; j < 8; j++){
        short h, l;
        split1(W1[(size_t)(k0 + j) * C1 + c], h, l);
        wfh[base + j] = (unsigned short)h;
        wfl[base + j] = (unsigned short)l;
    }
}

__global__ __launch_bounds__(256) void k_gemm1(
        const float* __restrict__ x,
        const unsigned short* __restrict__ wfh,
        const unsigned short* __restrict__ wfl,
        float* __restrict__ h1){
    int lane = threadIdx.x & 63;
    int wv   = threadIdx.x >> 6;
    int row0 = blockIdx.x * 64 + wv * 16;

    int arow = row0 + (lane & 15);
    if (arow >= N_NODES) arow = N_NODES - 1;     // clamp (stores guarded)
    const float* xp = x + (size_t)arow * F_INF + (lane >> 4) * 8;

    f32x4 acc[4];
    #pragma unroll
    for (int nt = 0; nt < 4; nt++) acc[nt] = (f32x4){0.f, 0.f, 0.f, 0.f};

    for (int ks = 0; ks < 16; ks++){
        float4 va = *(const float4*)(xp + ks * 32);
        float4 vb = *(const float4*)(xp + ks * 32 + 4);
        short8 ah, al;
        {
            float v[8] = {va.x, va.y, va.z, va.w, vb.x, vb.y, vb.z, vb.w};
            #pragma unroll
            for (int j = 0; j < 8; j++){ short h, l; split1(v[j], h, l); ah[j] = h; al[j] = l; }
        }
        const unsigned short* bh0 = wfh + ((size_t)(ks * 4) * 64 + lane) * 8;
        const unsigned short* bl0 = wfl + ((size_t)(ks * 4) * 64 + lane) * 8;
        #pragma unroll
        for (int nt = 0; nt < 4; nt++){
            short8 bh = *(const short8*)(bh0 + (size_t)nt * 64 * 8);
            short8 bl = *(const short8*)(bl0 + (size_t)nt * 64 * 8);
            acc[nt] = __builtin_amdgcn_mfma_f32_16x16x32_bf16(ah, bh, acc[nt], 0, 0, 0);
            acc[nt] = __builtin_amdgcn_mfma_f32_16x16x32_bf16(ah, bl, acc[nt], 0, 0, 0);
            acc[nt] = __builtin_amdgcn_mfma_f32_16x16x32_bf16(al, bh, acc[nt], 0, 0, 0);
        }
    }

    // C/D layout: col = lane&15, row = (lane>>4)*4 + reg   [m89-verified]
    int g = lane >> 4, c = lane & 15;
    #pragma unroll
    for (int nt = 0; nt < 4; nt++){
        #pragma unroll
        for (int r = 0; r < 4; r++){
            int row = row0 + g * 4 + r;
            if (row < N_NODES) h1[(size_t)row * C1 + nt * 16 + c] = acc[nt][r];
        }
    }
}

// ================= attention logits from h1 =================
__global__ void k_logits(const float* __restrict__ h1, const float* __restrict__ a1s,
                         const float* __restrict__ a1d,
                         float* __restrict__ als1, float* __restrict__ ald1){
    int t = blockIdx.x * 256 + threadIdx.x;
    if (t >= N_NODES * HEADS) return;
    int h = t & 7;
    const float* hp = h1 + (size_t)t * 8;
    float4 p = *(const float4*)(hp);
    float4 q = *(const float4*)(hp + 4);
    const float* as = a1s + h * 8;
    const float* ad = a1d + h * 8;
    float s = p.x*as[0] + p.y*as[1] + p.z*as[2] + p.w*as[3]
            + q.x*as[4] + q.y*as[5] + q.z*as[6] + q.w*as[7];
    float d = p.x*ad[0] + p.y*ad[1] + p.z*ad[2] + p.w*ad[3]
            + q.x*ad[4] + q.y*ad[5] + q.z*ad[6] + q.w*ad[7];
    als1[t] = s; ald1[t] = d;
}

// ================= layer1 aggregate + normalize + ELU + layer2 GEMM ========
// one wave per node; lane = feature. CSR gather, no atomics.
__global__ __launch_bounds__(256) void k_agg1(
        const int* __restrict__ csr_src, const int* __restrict__ ofs,
        const int* __restrict__ deg,
        const float* __restrict__ als1, const float* __restrict__ ald1,
        const float* __restrict__ h1,
        const float* __restrict__ b1, const float* __restrict__ W2,
        const float* __restrict__ a2s, const float* __restrict__ a2d,
        float* __restrict__ h2, float* __restrict__ als2, float* __restrict__ ald2){
    __shared__ float sh[4][C1];
    int lane = threadIdx.x & 63;
    int wv   = threadIdx.x >> 6;
    int n = blockIdx.x * 4 + wv;
    int h = lane >> 3;
    int start = ofs[n], dcount = deg[n];
    float aldv = ald1[n * HEADS + h];
    float acc = 0.f, dsum = 0.f;
    int i = 0;
    for (; i + 1 < dcount; i += 2){
        int s0 = csr_src[start + i];
        int s1 = csr_src[start + i + 1];
        float ex0 = expf(leaky(als1[s0 * HEADS + h] + aldv));
        float ex1 = expf(leaky(als1[s1 * HEADS + h] + aldv));
        acc = fmaf(ex0, h1[(size_t)s0 * C1 + lane], acc);
        acc = fmaf(ex1, h1[(size_t)s1 * C1 + lane], acc);
        dsum += ex0 + ex1;
    }
    if (i < dcount){
        int s0 = csr_src[start + i];
        float ex0 = expf(leaky(als1[s0 * HEADS + h] + aldv));
        acc = fmaf(ex0, h1[(size_t)s0 * C1 + lane], acc);
        dsum += ex0;
    }
    float v = acc / (dsum + 1e-16f) + b1[lane];
    float el = v > 0.f ? v : expm1f(v);
    sh[wv][lane] = el;
    __syncthreads();
    float hc = 0.f;
    if (lane < NCLS){
        #pragma unroll
        for (int k = 0; k < C1; k++) hc = fmaf(sh[wv][k], W2[k * NCLS + lane], hc);
        h2[n * NCLS + lane] = hc;
    }
    float ps = (lane < NCLS) ? hc * a2s[lane] : 0.f;
    float pd = (lane < NCLS) ? hc * a2d[lane] : 0.f;
    ps += __shfl_xor(ps, 1); ps += __shfl_xor(ps, 2); ps += __shfl_xor(ps, 4);
    pd += __shfl_xor(pd, 1); pd += __shfl_xor(pd, 2); pd += __shfl_xor(pd, 4);
    if (lane == 0){ als2[n] = ps; ald2[n] = pd; }
}

// ================= layer2 aggregate + log_softmax ==========================
// one wave per node; 8 groups x 8 lanes; group g walks edges g, g+8, ...
// c = lane&7: c<7 -> feature, c==7 -> denominator.
__global__ __launch_bounds__(256) void k_agg2(
        const int* __restrict__ csr_src, const int* __restrict__ ofs,
        const int* __restrict__ deg,
        const float* __restrict__ als2, const float* __restrict__ ald2,
        const float* __restrict__ h2, const float* __restrict__ b2,
        float* __restrict__ out){
    int lane = threadIdx.x & 63;
    int wv   = threadIdx.x >> 6;
    int n = blockIdx.x * 4 + wv;
    int c = lane & 7, g = lane >> 3;
    int start = ofs[n], dcount = deg[n];
    float aldv = ald2[n];
    float acc = 0.f;
    for (int i = g; i < dcount; i += 8){
        int s = csr_src[start + i];
        float ex = expf(leaky(als2[s] + aldv));
        acc += (c < NCLS) ? ex * h2[s * NCLS + c] : ex;
    }
    acc += __shfl_xor(acc, 8); acc += __shfl_xor(acc, 16); acc += __shfl_xor(acc, 32);
    float den = __shfl(acc, lane | 7) + 1e-16f;
    float v = acc / den + b2[c < NCLS ? c : 0];
    float vm = (c < NCLS) ? v : -INFINITY;
    vm = fmaxf(vm, __shfl_xor(vm, 1));
    vm = fmaxf(vm, __shfl_xor(vm, 2));
    vm = fmaxf(vm, __shfl_xor(vm, 4));
    float ev = (c < NCLS) ? expf(v - vm) : 0.f;
    ev += __shfl_xor(ev, 1); ev += __shfl_xor(ev, 2); ev += __shfl_xor(ev, 4);
    float lse = vm + logf(ev);
    if (g == 0 && c < NCLS) out[n * NCLS + c] = v - lse;
}

extern "C" void kernel_launch(void* const* d_in, const int* in_sizes, int n_in,
                              void* d_out, int out_size, void* d_ws, size_t ws_size,
                              hipStream_t stream){
    const float* x    = (const float*)d_in[0];
    const int*   ei   = (const int*)  d_in[1];
    const float* W1   = (const float*)d_in[2];
    const float* a1s  = (const float*)d_in[3];
    const float* a1d  = (const float*)d_in[4];
    const float* b1   = (const float*)d_in[5];
    const float* W2   = (const float*)d_in[6];
    const float* a2s  = (const float*)d_in[7];
    const float* a2d  = (const float*)d_in[8];
    const float* b2   = (const float*)d_in[9];
    float* out = (float*)d_out;

    float* w = (float*)d_ws;
    float*    h1   = w;              w += (size_t)N_NODES * C1;
    float*    als1 = w;              w += N_NODES * HEADS;
    float*    ald1 = w;              w += N_NODES * HEADS;
    float*    h2   = w;              w += N_NODES * NCLS;
    float*    als2 = w;              w += N_NODES;
    float*    ald2 = w;              w += N_NODES;
    unsigned short* wfh = (unsigned short*)w;  w += (16 * 4 * 64 * 8) / 2;
    unsigned short* wfl = (unsigned short*)w;  w += (16 * 4 * 64 * 8) / 2;
    int* deg     = (int*)w;          w += N_NODES;
    int* cur     = (int*)w;          w += N_NODES;
    int* ofs     = (int*)w;          w += N_NODES;
    int* csr_src = (int*)w;          w += ETOT;

    k_zero   <<<(N_NODES + 255) / 256, 256, 0, stream>>>(deg);
    k_hist   <<<(E_EDGES + 255) / 256, 256, 0, stream>>>(ei, deg);
    k_scan   <<<1, SCAN_T, 0, stream>>>(deg, ofs, cur, csr_src);
    k_scatter<<<(E_EDGES + 255) / 256, 256, 0, stream>>>(ei, ofs, cur, csr_src);
    k_wprep  <<<16, 256, 0, stream>>>(W1, wfh, wfl);
    k_gemm1  <<<(N_NODES + 63) / 64, 256, 0, stream>>>(x, wfh, wfl, h1);
    k_logits <<<(N_NODES * HEADS + 255) / 256, 256, 0, stream>>>(h1, a1s, a1d, als1, ald1);
    k_agg1   <<<N_NODES / 4, 256, 0, stream>>>(csr_src, ofs, deg, als1, ald1, h1,
                                               b1, W2, a2s, a2d, h2, als2, ald2);
    k_agg2   <<<N_NODES / 4, 256, 0, stream>>>(csr_src, ofs, deg, als2, ald2, h2, b2, out);
}

// Round 8
// 258.336 us; speedup vs baseline: 3.5522x; 1.4610x over previous
//
#include <hip/hip_runtime.h>
#include <math.h>

#define N_NODES 50000
#define E_EDGES 800000
#define ETOT    850000   // E + N self loops
#define F_INF   512
#define HEADS   8
#define C1      64       // HEADS*HID
#define NCLS    7
#define SLOPE   0.2f
#define NBLK    196      // ceil(N_NODES/256)

typedef __attribute__((ext_vector_type(8))) short short8;
typedef __attribute__((ext_vector_type(4))) float f32x4;

__device__ __forceinline__ float leaky(float x){ return x > 0.f ? x : SLOPE * x; }

// split f32 -> bf16 hi (truncated) + bf16 lo (RNE of residual)
__device__ __forceinline__ void split1(float v, short& h, short& l){
    unsigned u = __float_as_uint(v);
    unsigned hw = u >> 16;
    float fh = __uint_as_float(hw << 16);
    float r  = v - fh;
    unsigned ul = __float_as_uint(r);
    unsigned lw = (ul + 0x7fffu + ((ul >> 16) & 1u)) >> 16;
    h = (short)hw; l = (short)lw;
}

// ================= CSR build =================
__global__ void k_zero(int* deg){
    int n = blockIdx.x * 256 + threadIdx.x;
    if (n < N_NODES) deg[n] = 1;          // self loop
}

__global__ void k_hist(const int* __restrict__ ei, int* __restrict__ deg){
    int e = blockIdx.x * 256 + threadIdx.x;
    if (e < E_EDGES) atomicAdd(&deg[ei[E_EDGES + e]], 1);
}

// level 1: per-block sums of deg
__global__ __launch_bounds__(256) void k_bsum(const int* __restrict__ deg,
                                              int* __restrict__ bsum){
    __shared__ int ws[4];
    int n = blockIdx.x * 256 + threadIdx.x;
    int v = (n < N_NODES) ? deg[n] : 0;
    #pragma unroll
    for (int o = 1; o < 64; o <<= 1) v += __shfl_xor(v, o);
    int lane = threadIdx.x & 63, wv = threadIdx.x >> 6;
    if (lane == 0) ws[wv] = v;
    __syncthreads();
    if (threadIdx.x == 0) bsum[blockIdx.x] = ws[0] + ws[1] + ws[2] + ws[3];
}

// level 2: exclusive scan of the NBLK block sums (single tiny block)
__global__ __launch_bounds__(256) void k_bscan(const int* __restrict__ bsum,
                                               int* __restrict__ bbase){
    __shared__ int sp[256];
    int t = threadIdx.x;
    int v = (t < NBLK) ? bsum[t] : 0;
    sp[t] = v;
    __syncthreads();
    #pragma unroll
    for (int d = 1; d < 256; d <<= 1){
        int u = (t >= d) ? sp[t - d] : 0;
        __syncthreads();
        sp[t] += u;
        __syncthreads();
    }
    if (t < NBLK) bbase[t] = sp[t] - v;   // exclusive
}

// level 3: in-block exclusive scan + base -> ofs, cur=0, self-loop slot
__global__ __launch_bounds__(256) void k_apply(const int* __restrict__ deg,
                                               const int* __restrict__ bbase,
                                               int* __restrict__ ofs,
                                               int* __restrict__ cur,
                                               int* __restrict__ csr_src){
    __shared__ int sp[256];
    int t = threadIdx.x;
    int n = blockIdx.x * 256 + t;
    int v = (n < N_NODES) ? deg[n] : 0;
    sp[t] = v;
    __syncthreads();
    #pragma unroll
    for (int d = 1; d < 256; d <<= 1){
        int u = (t >= d) ? sp[t - d] : 0;
        __syncthreads();
        sp[t] += u;
        __syncthreads();
    }
    if (n < N_NODES){
        int o = bbase[blockIdx.x] + sp[t] - v;
        ofs[n] = o;
        cur[n] = 0;
        csr_src[o + v - 1] = n;           // self-loop in last slot
    }
}

__global__ void k_scatter(const int* __restrict__ ei, const int* __restrict__ ofs,
                          int* __restrict__ cur, int* __restrict__ csr_src){
    int e = blockIdx.x * 256 + threadIdx.x;
    if (e >= E_EDGES) return;
    int d = ei[E_EDGES + e];
    int p = atomicAdd(&cur[d], 1);
    csr_src[ofs[d] + p] = ei[e];
}

// ================= layer 1 GEMM (split-bf16 MFMA) =================
__global__ void k_wprep(const float* __restrict__ W1,
                        unsigned short* __restrict__ wfh,
                        unsigned short* __restrict__ wfl){
    int t = blockIdx.x * 256 + threadIdx.x;      // 4096 threads
    int lane = t & 63, nt = (t >> 6) & 3, ks = t >> 8;
    int c  = nt * 16 + (lane & 15);
    int k0 = ks * 32 + (lane >> 4) * 8;
    size_t base = ((size_t)(ks * 4 + nt) * 64 + lane) * 8;
    #pragma unroll
    for (int j = 0; j < 8; j++){
        short h, l;
        split1(W1[(size_t)(k0 + j) * C1 + c], h, l);
        wfh[base + j] = (unsigned short)h;
        wfl[base + j] = (unsigned short)l;
    }
}

__global__ __launch_bounds__(256) void k_gemm1(
        const float* __restrict__ x,
        const unsigned short* __restrict__ wfh,
        const unsigned short* __restrict__ wfl,
        float* __restrict__ h1){
    int lane = threadIdx.x & 63;
    int wv   = threadIdx.x >> 6;
    int row0 = blockIdx.x * 64 + wv * 16;

    int arow = row0 + (lane & 15);
    if (arow >= N_NODES) arow = N_NODES - 1;     // clamp (stores guarded)
    const float* xp = x + (size_t)arow * F_INF + (lane >> 4) * 8;

    f32x4 acc[4];
    #pragma unroll
    for (int nt = 0; nt < 4; nt++) acc[nt] = (f32x4){0.f, 0.f, 0.f, 0.f};

    for (int ks = 0; ks < 16; ks++){
        float4 va = *(const float4*)(xp + ks * 32);
        float4 vb = *(const float4*)(xp + ks * 32 + 4);
        short8 ah, al;
        {
            float v[8] = {va.x, va.y, va.z, va.w, vb.x, vb.y, vb.z, vb.w};
            #pragma unroll
            for (int j = 0; j < 8; j++){ short h, l; split1(v[j], h, l); ah[j] = h; al[j] = l; }
        }
        const unsigned short* bh0 = wfh + ((size_t)(ks * 4) * 64 + lane) * 8;
        const unsigned short* bl0 = wfl + ((size_t)(ks * 4) * 64 + lane) * 8;
        #pragma unroll
        for (int nt = 0; nt < 4; nt++){
            short8 bh = *(const short8*)(bh0 + (size_t)nt * 64 * 8);
            short8 bl = *(const short8*)(bl0 + (size_t)nt * 64 * 8);
            acc[nt] = __builtin_amdgcn_mfma_f32_16x16x32_bf16(ah, bh, acc[nt], 0, 0, 0);
            acc[nt] = __builtin_amdgcn_mfma_f32_16x16x32_bf16(ah, bl, acc[nt], 0, 0, 0);
            acc[nt] = __builtin_amdgcn_mfma_f32_16x16x32_bf16(al, bh, acc[nt], 0, 0, 0);
        }
    }

    // C/D layout: col = lane&15, row = (lane>>4)*4 + reg   [m89-verified]
    int g = lane >> 4, c = lane & 15;
    #pragma unroll
    for (int nt = 0; nt < 4; nt++){
        #pragma unroll
        for (int r = 0; r < 4; r++){
            int row = row0 + g * 4 + r;
            if (row < N_NODES) h1[(size_t)row * C1 + nt * 16 + c] = acc[nt][r];
        }
    }
}

// ================= attention logits from h1 =================
__global__ void k_logits(const float* __restrict__ h1, const float* __restrict__ a1s,
                         const float* __restrict__ a1d,
                         float* __restrict__ als1, float* __restrict__ ald1){
    int t = blockIdx.x * 256 + threadIdx.x;
    if (t >= N_NODES * HEADS) return;
    int h = t & 7;
    const float* hp = h1 + (size_t)t * 8;
    float4 p = *(const float4*)(hp);
    float4 q = *(const float4*)(hp + 4);
    const float* as = a1s + h * 8;
    const float* ad = a1d + h * 8;
    float s = p.x*as[0] + p.y*as[1] + p.z*as[2] + p.w*as[3]
            + q.x*as[4] + q.y*as[5] + q.z*as[6] + q.w*as[7];
    float d = p.x*ad[0] + p.y*ad[1] + p.z*ad[2] + p.w*ad[3]
            + q.x*ad[4] + q.y*ad[5] + q.z*ad[6] + q.w*ad[7];
    als1[t] = s; ald1[t] = d;
}

// ================= layer1 aggregate + normalize + ELU + layer2 GEMM ========
// one wave per node; lane = feature. CSR gather, no atomics.
__global__ __launch_bounds__(256) void k_agg1(
        const int* __restrict__ csr_src, const int* __restrict__ ofs,
        const int* __restrict__ deg,
        const float* __restrict__ als1, const float* __restrict__ ald1,
        const float* __restrict__ h1,
        const float* __restrict__ b1, const float* __restrict__ W2,
        const float* __restrict__ a2s, const float* __restrict__ a2d,
        float* __restrict__ h2, float* __restrict__ als2, float* __restrict__ ald2){
    __shared__ float sh[4][C1];
    int lane = threadIdx.x & 63;
    int wv   = threadIdx.x >> 6;
    int n = blockIdx.x * 4 + wv;
    int h = lane >> 3;
    int start = ofs[n], dcount = deg[n];
    float aldv = ald1[n * HEADS + h];
    float acc = 0.f, dsum = 0.f;
    int i = 0;
    for (; i + 1 < dcount; i += 2){
        int s0 = csr_src[start + i];
        int s1 = csr_src[start + i + 1];
        float ex0 = expf(leaky(als1[s0 * HEADS + h] + aldv));
        float ex1 = expf(leaky(als1[s1 * HEADS + h] + aldv));
        acc = fmaf(ex0, h1[(size_t)s0 * C1 + lane], acc);
        acc = fmaf(ex1, h1[(size_t)s1 * C1 + lane], acc);
        dsum += ex0 + ex1;
    }
    if (i < dcount){
        int s0 = csr_src[start + i];
        float ex0 = expf(leaky(als1[s0 * HEADS + h] + aldv));
        acc = fmaf(ex0, h1[(size_t)s0 * C1 + lane], acc);
        dsum += ex0;
    }
    float v = acc / (dsum + 1e-16f) + b1[lane];
    float el = v > 0.f ? v : expm1f(v);
    sh[wv][lane] = el;
    __syncthreads();
    float hc = 0.f;
    if (lane < NCLS){
        #pragma unroll
        for (int k = 0; k < C1; k++) hc = fmaf(sh[wv][k], W2[k * NCLS + lane], hc);
        h2[n * NCLS + lane] = hc;
    }
    float ps = (lane < NCLS) ? hc * a2s[lane] : 0.f;
    float pd = (lane < NCLS) ? hc * a2d[lane] : 0.f;
    ps += __shfl_xor(ps, 1); ps += __shfl_xor(ps, 2); ps += __shfl_xor(ps, 4);
    pd += __shfl_xor(pd, 1); pd += __shfl_xor(pd, 2); pd += __shfl_xor(pd, 4);
    if (lane == 0){ als2[n] = ps; ald2[n] = pd; }
}

// ================= layer2 aggregate + log_softmax ==========================
// one wave per node; 8 groups x 8 lanes; group g walks edges g, g+8, ...
// c = lane&7: c<7 -> feature, c==7 -> denominator.
__global__ __launch_bounds__(256) void k_agg2(
        const int* __restrict__ csr_src, const int* __restrict__ ofs,
        const int* __restrict__ deg,
        const float* __restrict__ als2, const float* __restrict__ ald2,
        const float* __restrict__ h2, const float* __restrict__ b2,
        float* __restrict__ out){
    int lane = threadIdx.x & 63;
    int wv   = threadIdx.x >> 6;
    int n = blockIdx.x * 4 + wv;
    int c = lane & 7, g = lane >> 3;
    int start = ofs[n], dcount = deg[n];
    float aldv = ald2[n];
    float acc = 0.f;
    for (int i = g; i < dcount; i += 8){
        int s = csr_src[start + i];
        float ex = expf(leaky(als2[s] + aldv));
        acc += (c < NCLS) ? ex * h2[s * NCLS + c] : ex;
    }
    acc += __shfl_xor(acc, 8); acc += __shfl_xor(acc, 16); acc += __shfl_xor(acc, 32);
    float den = __shfl(acc, lane | 7) + 1e-16f;
    float v = acc / den + b2[c < NCLS ? c : 0];
    float vm = (c < NCLS) ? v : -INFINITY;
    vm = fmaxf(vm, __shfl_xor(vm, 1));
    vm = fmaxf(vm, __shfl_xor(vm, 2));
    vm = fmaxf(vm, __shfl_xor(vm, 4));
    float ev = (c < NCLS) ? expf(v - vm) : 0.f;
    ev += __shfl_xor(ev, 1); ev += __shfl_xor(ev, 2); ev += __shfl_xor(ev, 4);
    float lse = vm + logf(ev);
    if (g == 0 && c < NCLS) out[n * NCLS + c] = v - lse;
}

extern "C" void kernel_launch(void* const* d_in, const int* in_sizes, int n_in,
                              void* d_out, int out_size, void* d_ws, size_t ws_size,
                              hipStream_t stream){
    const float* x    = (const float*)d_in[0];
    const int*   ei   = (const int*)  d_in[1];
    const float* W1   = (const float*)d_in[2];
    const float* a1s  = (const float*)d_in[3];
    const float* a1d  = (const float*)d_in[4];
    const float* b1   = (const float*)d_in[5];
    const float* W2   = (const float*)d_in[6];
    const float* a2s  = (const float*)d_in[7];
    const float* a2d  = (const float*)d_in[8];
    const float* b2   = (const float*)d_in[9];
    float* out = (float*)d_out;

    float* w = (float*)d_ws;
    float*    h1   = w;              w += (size_t)N_NODES * C1;
    float*    als1 = w;              w += N_NODES * HEADS;
    float*    ald1 = w;              w += N_NODES * HEADS;
    float*    h2   = w;              w += N_NODES * NCLS;
    float*    als2 = w;              w += N_NODES;
    float*    ald2 = w;              w += N_NODES;
    unsigned short* wfh = (unsigned short*)w;  w += (16 * 4 * 64 * 8) / 2;
    unsigned short* wfl = (unsigned short*)w;  w += (16 * 4 * 64 * 8) / 2;
    int* deg     = (int*)w;          w += N_NODES;
    int* cur     = (int*)w;          w += N_NODES;
    int* ofs     = (int*)w;          w += N_NODES;
    int* bsum    = (int*)w;          w += 256;
    int* bbase   = (int*)w;          w += 256;
    int* csr_src = (int*)w;          w += ETOT;

    k_zero   <<<NBLK, 256, 0, stream>>>(deg);
    k_hist   <<<(E_EDGES + 255) / 256, 256, 0, stream>>>(ei, deg);
    k_bsum   <<<NBLK, 256, 0, stream>>>(deg, bsum);
    k_bscan  <<<1, 256, 0, stream>>>(bsum, bbase);
    k_apply  <<<NBLK, 256, 0, stream>>>(deg, bbase, ofs, cur, csr_src);
    k_scatter<<<(E_EDGES + 255) / 256, 256, 0, stream>>>(ei, ofs, cur, csr_src);
    k_wprep  <<<16, 256, 0, stream>>>(W1, wfh, wfl);
    k_gemm1  <<<(N_NODES + 63) / 64, 256, 0, stream>>>(x, wfh, wfl, h1);
    k_logits <<<(N_NODES * HEADS + 255) / 256, 256, 0, stream>>>(h1, a1s, a1d, als1, ald1);
    k_agg1   <<<N_NODES / 4, 256, 0, stream>>>(csr_src, ofs, deg, als1, ald1, h1,
                                               b1, W2, a2s, a2d, h2, als2, ald2);
    k_agg2   <<<N_NODES / 4, 256, 0, stream>>>(csr_src, ofs, deg, als2, ald2, h2, b2, out);
}

// Round 10
// 225.949 us; speedup vs baseline: 4.0614x; 1.1433x over previous
//
#include <hip/hip_runtime.h>
#include <math.h>

#define N_NODES 50000
#define E_EDGES 800000
#define ETOT    850000   // E + N self loops
#define F_INF   512
#define HEADS   8
#define C1      64       // HEADS*HID
#define NCLS    7
#define SLOPE   0.2f
#define NBLK    196      // ceil(N_NODES/256)

typedef __attribute__((ext_vector_type(8))) short short8;
typedef __attribute__((ext_vector_type(4))) float f32x4;

__device__ __forceinline__ float leaky(float x){ return x > 0.f ? x : SLOPE * x; }

// split f32 -> bf16 hi (truncated) + bf16 lo (RNE of residual)
__device__ __forceinline__ void split1(float v, short& h, short& l){
    unsigned u = __float_as_uint(v);
    unsigned hw = u >> 16;
    float fh = __uint_as_float(hw << 16);
    float r  = v - fh;
    unsigned ul = __float_as_uint(r);
    unsigned lw = (ul + 0x7fffu + ((ul >> 16) & 1u)) >> 16;
    h = (short)hw; l = (short)lw;
}

__device__ __forceinline__ unsigned short rne_bf16(float v){
    unsigned u = __float_as_uint(v);
    return (unsigned short)((u + 0x7fffu + ((u >> 16) & 1u)) >> 16);
}
__device__ __forceinline__ float bf_to_f(unsigned short us){
    return __uint_as_float((unsigned)us << 16);
}

// ================= CSR build =================
__global__ void k_zero(int* deg){
    int n = blockIdx.x * 256 + threadIdx.x;
    if (n < N_NODES) deg[n] = 1;          // self loop
}

__global__ void k_hist(const int* __restrict__ ei, int* __restrict__ deg){
    int e = blockIdx.x * 256 + threadIdx.x;
    if (e < E_EDGES) atomicAdd(&deg[ei[E_EDGES + e]], 1);
}

// level 1: per-block sums of deg
__global__ __launch_bounds__(256) void k_bsum(const int* __restrict__ deg,
                                              int* __restrict__ bsum){
    __shared__ int ws[4];
    int n = blockIdx.x * 256 + threadIdx.x;
    int v = (n < N_NODES) ? deg[n] : 0;
    #pragma unroll
    for (int o = 1; o < 64; o <<= 1) v += __shfl_xor(v, o);
    int lane = threadIdx.x & 63, wv = threadIdx.x >> 6;
    if (lane == 0) ws[wv] = v;
    __syncthreads();
    if (threadIdx.x == 0) bsum[blockIdx.x] = ws[0] + ws[1] + ws[2] + ws[3];
}

// level 2: exclusive scan of the NBLK block sums (single tiny block)
__global__ __launch_bounds__(256) void k_bscan(const int* __restrict__ bsum,
                                               int* __restrict__ bbase){
    __shared__ int sp[256];
    int t = threadIdx.x;
    int v = (t < NBLK) ? bsum[t] : 0;
    sp[t] = v;
    __syncthreads();
    #pragma unroll
    for (int d = 1; d < 256; d <<= 1){
        int u = (t >= d) ? sp[t - d] : 0;
        __syncthreads();
        sp[t] += u;
        __syncthreads();
    }
    if (t < NBLK) bbase[t] = sp[t] - v;   // exclusive
}

// level 3: in-block exclusive scan + base -> ofs, cur=0, self-loop slot
__global__ __launch_bounds__(256) void k_apply(const int* __restrict__ deg,
                                               const int* __restrict__ bbase,
                                               int* __restrict__ ofs,
                                               int* __restrict__ cur,
                                               int* __restrict__ csr_src){
    __shared__ int sp[256];
    int t = threadIdx.x;
    int n = blockIdx.x * 256 + t;
    int v = (n < N_NODES) ? deg[n] : 0;
    sp[t] = v;
    __syncthreads();
    #pragma unroll
    for (int d = 1; d < 256; d <<= 1){
        int u = (t >= d) ? sp[t - d] : 0;
        __syncthreads();
        sp[t] += u;
        __syncthreads();
    }
    if (n < N_NODES){
        int o = bbase[blockIdx.x] + sp[t] - v;
        ofs[n] = o;
        cur[n] = 0;
        csr_src[o + v - 1] = n;           // self-loop in last slot
    }
}

__global__ void k_scatter(const int* __restrict__ ei, const int* __restrict__ ofs,
                          int* __restrict__ cur, int* __restrict__ csr_src){
    int e = blockIdx.x * 256 + threadIdx.x;
    if (e >= E_EDGES) return;
    int d = ei[E_EDGES + e];
    int p = atomicAdd(&cur[d], 1);
    csr_src[ofs[d] + p] = ei[e];
}

// ================= layer 1 GEMM (split-bf16 MFMA) =================
__global__ void k_wprep(const float* __restrict__ W1,
                        unsigned short* __restrict__ wfh,
                        unsigned short* __restrict__ wfl){
    int t = blockIdx.x * 256 + threadIdx.x;      // 4096 threads
    int lane = t & 63, nt = (t >> 6) & 3, ks = t >> 8;
    int c  = nt * 16 + (lane & 15);
    int k0 = ks * 32 + (lane >> 4) * 8;
    size_t base = ((size_t)(ks * 4 + nt) * 64 + lane) * 8;
    #pragma unroll
    for (int j = 0; j < 8; j++){
        short h, l;
        split1(W1[(size_t)(k0 + j) * C1 + c], h, l);
        wfh[base + j] = (unsigned short)h;
        wfl[base + j] = (unsigned short)l;
    }
}

__global__ __launch_bounds__(256) void k_gemm1(
        const float* __restrict__ x,
        const unsigned short* __restrict__ wfh,
        const unsigned short* __restrict__ wfl,
        float* __restrict__ h1, unsigned short* __restrict__ h1b){
    int lane = threadIdx.x & 63;
    int wv   = threadIdx.x >> 6;
    int row0 = blockIdx.x * 64 + wv * 16;

    int arow = row0 + (lane & 15);
    if (arow >= N_NODES) arow = N_NODES - 1;     // clamp (stores guarded)
    const float* xp = x + (size_t)arow * F_INF + (lane >> 4) * 8;

    f32x4 acc[4];
    #pragma unroll
    for (int nt = 0; nt < 4; nt++) acc[nt] = (f32x4){0.f, 0.f, 0.f, 0.f};

    for (int ks = 0; ks < 16; ks++){
        float4 va = *(const float4*)(xp + ks * 32);
        float4 vb = *(const float4*)(xp + ks * 32 + 4);
        short8 ah, al;
        {
            float v[8] = {va.x, va.y, va.z, va.w, vb.x, vb.y, vb.z, vb.w};
            #pragma unroll
            for (int j = 0; j < 8; j++){ short h, l; split1(v[j], h, l); ah[j] = h; al[j] = l; }
        }
        const unsigned short* bh0 = wfh + ((size_t)(ks * 4) * 64 + lane) * 8;
        const unsigned short* bl0 = wfl + ((size_t)(ks * 4) * 64 + lane) * 8;
        #pragma unroll
        for (int nt = 0; nt < 4; nt++){
            short8 bh = *(const short8*)(bh0 + (size_t)nt * 64 * 8);
            short8 bl = *(const short8*)(bl0 + (size_t)nt * 64 * 8);
            acc[nt] = __builtin_amdgcn_mfma_f32_16x16x32_bf16(ah, bh, acc[nt], 0, 0, 0);
            acc[nt] = __builtin_amdgcn_mfma_f32_16x16x32_bf16(ah, bl, acc[nt], 0, 0, 0);
            acc[nt] = __builtin_amdgcn_mfma_f32_16x16x32_bf16(al, bh, acc[nt], 0, 0, 0);
        }
    }

    // C/D layout: col = lane&15, row = (lane>>4)*4 + reg   [m89-verified]
    int g = lane >> 4, c = lane & 15;
    #pragma unroll
    for (int nt = 0; nt < 4; nt++){
        #pragma unroll
        for (int r = 0; r < 4; r++){
            int row = row0 + g * 4 + r;
            if (row < N_NODES){
                h1 [(size_t)row * C1 + nt * 16 + c] = acc[nt][r];
                h1b[(size_t)row * C1 + nt * 16 + c] = rne_bf16(acc[nt][r]);
            }
        }
    }
}

// ================= attention logits from h1 =================
__global__ void k_logits(const float* __restrict__ h1, const float* __restrict__ a1s,
                         const float* __restrict__ a1d,
                         float* __restrict__ als1, float* __restrict__ ald1){
    int t = blockIdx.x * 256 + threadIdx.x;
    if (t >= N_NODES * HEADS) return;
    int h = t & 7;
    const float* hp = h1 + (size_t)t * 8;
    float4 p = *(const float4*)(hp);
    float4 q = *(const float4*)(hp + 4);
    const float* as = a1s + h * 8;
    const float* ad = a1d + h * 8;
    float s = p.x*as[0] + p.y*as[1] + p.z*as[2] + p.w*as[3]
            + q.x*as[4] + q.y*as[5] + q.z*as[6] + q.w*as[7];
    float d = p.x*ad[0] + p.y*ad[1] + p.z*ad[2] + p.w*ad[3]
            + q.x*ad[4] + q.y*ad[5] + q.z*ad[6] + q.w*ad[7];
    als1[t] = s; ald1[t] = d;
}

// ================= layer1 aggregate + normalize + ELU + layer2 GEMM ========
// one wave per node; lane = feature. 8-wide predicated unroll, bf16 gather.
__global__ __launch_bounds__(256) void k_agg1(
        const int* __restrict__ csr_src, const int* __restrict__ ofs,
        const int* __restrict__ deg,
        const float* __restrict__ als1, const float* __restrict__ ald1,
        const unsigned short* __restrict__ h1b,
        const float* __restrict__ b1, const float* __restrict__ W2,
        const float* __restrict__ a2s, const float* __restrict__ a2d,
        float* __restrict__ h2, float* __restrict__ als2, float* __restrict__ ald2){
    __shared__ float sh[4][C1];
    int lane = threadIdx.x & 63;
    int wv   = threadIdx.x >> 6;
    int n = blockIdx.x * 4 + wv;
    int h = lane >> 3;
    int start = ofs[n], dcount = deg[n];
    int end = start + dcount;
    float aldv = ald1[n * HEADS + h];
    float acc = 0.f, dsum = 0.f;
    for (int i = start; i < end; i += 8){
        int sv[8]; float ex[8];
        #pragma unroll
        for (int j = 0; j < 8; j++){
            int id = i + j;
            sv[j] = csr_src[id < end ? id : end - 1];
        }
        #pragma unroll
        for (int j = 0; j < 8; j++){
            float v = leaky(als1[sv[j] * HEADS + h] + aldv);
            ex[j] = (i + j < end) ? __expf(v) : 0.f;
        }
        #pragma unroll
        for (int j = 0; j < 8; j++){
            float hv = bf_to_f(h1b[(size_t)sv[j] * C1 + lane]);
            acc = fmaf(ex[j], hv, acc);
            dsum += ex[j];
        }
    }
    float v = acc / (dsum + 1e-16f) + b1[lane];
    float el = v > 0.f ? v : expm1f(v);
    sh[wv][lane] = el;
    __syncthreads();
    float hc = 0.f;
    if (lane < NCLS){
        #pragma unroll
        for (int k = 0; k < C1; k++) hc = fmaf(sh[wv][k], W2[k * NCLS + lane], hc);
        h2[n * NCLS + lane] = hc;
    }
    float ps = (lane < NCLS) ? hc * a2s[lane] : 0.f;
    float pd = (lane < NCLS) ? hc * a2d[lane] : 0.f;
    ps += __shfl_xor(ps, 1); ps += __shfl_xor(ps, 2); ps += __shfl_xor(ps, 4);
    pd += __shfl_xor(pd, 1); pd += __shfl_xor(pd, 2); pd += __shfl_xor(pd, 4);
    if (lane == 0){ als2[n] = ps; ald2[n] = pd; }
}

// ================= layer2 aggregate + log_softmax ==========================
// one wave per node; 8 groups x 8 lanes; group g walks edges g, g+8, ...
// c = lane&7: c<7 -> feature, c==7 -> denominator.
__global__ __launch_bounds__(256) void k_agg2(
        const int* __restrict__ csr_src, const int* __restrict__ ofs,
        const int* __restrict__ deg,
        const float* __restrict__ als2, const float* __restrict__ ald2,
        const float* __restrict__ h2, const float* __restrict__ b2,
        float* __restrict__ out){
    int lane = threadIdx.x & 63;
    int wv   = threadIdx.x >> 6;
    int n = blockIdx.x * 4 + wv;
    int c = lane & 7, g = lane >> 3;
    int start = ofs[n], dcount = deg[n];
    float aldv = ald2[n];
    float acc = 0.f;
    for (int i = g; i < dcount; i += 8){
        int s = csr_src[start + i];
        float ex = __expf(leaky(als2[s] + aldv));
        acc += (c < NCLS) ? ex * h2[s * NCLS + c] : ex;
    }
    acc += __shfl_xor(acc, 8); acc += __shfl_xor(acc, 16); acc += __shfl_xor(acc, 32);
    float den = __shfl(acc, lane | 7) + 1e-16f;
    float v = acc / den + b2[c < NCLS ? c : 0];
    float vm = (c < NCLS) ? v : -INFINITY;
    vm = fmaxf(vm, __shfl_xor(vm, 1));
    vm = fmaxf(vm, __shfl_xor(vm, 2));
    vm = fmaxf(vm, __shfl_xor(vm, 4));
    float ev = (c < NCLS) ? __expf(v - vm) : 0.f;
    ev += __shfl_xor(ev, 1); ev += __shfl_xor(ev, 2); ev += __shfl_xor(ev, 4);
    float lse = vm + logf(ev);
    if (g == 0 && c < NCLS) out[n * NCLS + c] = v - lse;
}

extern "C" void kernel_launch(void* const* d_in, const int* in_sizes, int n_in,
                              void* d_out, int out_size, void* d_ws, size_t ws_size,
                              hipStream_t stream){
    const float* x    = (const float*)d_in[0];
    const int*   ei   = (const int*)  d_in[1];
    const float* W1   = (const float*)d_in[2];
    const float* a1s  = (const float*)d_in[3];
    const float* a1d  = (const float*)d_in[4];
    const float* b1   = (const float*)d_in[5];
    const float* W2   = (const float*)d_in[6];
    const float* a2s  = (const float*)d_in[7];
    const float* a2d  = (const float*)d_in[8];
    const float* b2   = (const float*)d_in[9];
    float* out = (float*)d_out;

    float* w = (float*)d_ws;
    float*    h1   = w;              w += (size_t)N_NODES * C1;
    unsigned short* h1b = (unsigned short*)w;  w += (size_t)N_NODES * C1 / 2;
    float*    als1 = w;              w += N_NODES * HEADS;
    float*    ald1 = w;              w += N_NODES * HEADS;
    float*    h2   = w;              w += N_NODES * NCLS;
    float*    als2 = w;              w += N_NODES;
    float*    ald2 = w;              w += N_NODES;
    unsigned short* wfh = (unsigned short*)w;  w += (16 * 4 * 64 * 8) / 2;
    unsigned short* wfl = (unsigned short*)w;  w += (16 * 4 * 64 * 8) / 2;
    int* deg     = (int*)w;          w += N_NODES;
    int* cur     = (int*)w;          w += N_NODES;
    int* ofs     = (int*)w;          w += N_NODES;
    int* bsum    = (int*)w;          w += 256;
    int* bbase   = (int*)w;          w += 256;
    int* csr_src = (int*)w;          w += ETOT;

    k_zero   <<<NBLK, 256, 0, stream>>>(deg);
    k_hist   <<<(E_EDGES + 255) / 256, 256, 0, stream>>>(ei, deg);
    k_bsum   <<<NBLK, 256, 0, stream>>>(deg, bsum);
    k_bscan  <<<1, 256, 0, stream>>>(bsum, bbase);
    k_apply  <<<NBLK, 256, 0, stream>>>(deg, bbase, ofs, cur, csr_src);
    k_scatter<<<(E_EDGES + 255) / 256, 256, 0, stream>>>(ei, ofs, cur, csr_src);
    k_wprep  <<<16, 256, 0, stream>>>(W1, wfh, wfl);
    k_gemm1  <<<(N_NODES + 63) / 64, 256, 0, stream>>>(x, wfh, wfl, h1, h1b);
    k_logits <<<(N_NODES * HEADS + 255) / 256, 256, 0, stream>>>(h1, a1s, a1d, als1, ald1);
    k_agg1   <<<N_NODES / 4, 256, 0, stream>>>(csr_src, ofs, deg, als1, ald1, h1b,
                                               b1, W2, a2s, a2d, h2, als2, ald2);
    k_agg2   <<<N_NODES / 4, 256, 0, stream>>>(csr_src, ofs, deg, als2, ald2, h2, b2, out);
}

// Round 11
// 213.599 us; speedup vs baseline: 4.2962x; 1.0578x over previous
//
#include <hip/hip_runtime.h>
#include <math.h>

#define N_NODES 50000
#define E_EDGES 800000
#define ETOT    850000   // E + N self loops
#define F_INF   512
#define HEADS   8
#define C1      64       // HEADS*HID
#define NCLS    7
#define SLOPE   0.2f
#define NBLK    196      // ceil(N_NODES/256)

typedef __attribute__((ext_vector_type(8))) short short8;
typedef __attribute__((ext_vector_type(4))) float f32x4;

__device__ __forceinline__ float leaky(float x){ return x > 0.f ? x : SLOPE * x; }

// split f32 -> bf16 hi (truncated) + bf16 lo (RNE of residual)
__device__ __forceinline__ void split1(float v, short& h, short& l){
    unsigned u = __float_as_uint(v);
    unsigned hw = u >> 16;
    float fh = __uint_as_float(hw << 16);
    float r  = v - fh;
    unsigned ul = __float_as_uint(r);
    unsigned lw = (ul + 0x7fffu + ((ul >> 16) & 1u)) >> 16;
    h = (short)hw; l = (short)lw;
}

__device__ __forceinline__ unsigned short rne_bf16(float v){
    unsigned u = __float_as_uint(v);
    return (unsigned short)((u + 0x7fffu + ((u >> 16) & 1u)) >> 16);
}
__device__ __forceinline__ float bf_to_f(unsigned short us){
    return __uint_as_float((unsigned)us << 16);
}

// ================= CSR build =================
__global__ void k_zero(int* deg){
    int n = blockIdx.x * 256 + threadIdx.x;
    if (n < N_NODES) deg[n] = 1;          // self loop
}

__global__ void k_hist(const int* __restrict__ ei, int* __restrict__ deg){
    int e = blockIdx.x * 256 + threadIdx.x;
    if (e < E_EDGES) atomicAdd(&deg[ei[E_EDGES + e]], 1);
}

// level 1: per-block sums of deg
__global__ __launch_bounds__(256) void k_bsum(const int* __restrict__ deg,
                                              int* __restrict__ bsum){
    __shared__ int ws[4];
    int n = blockIdx.x * 256 + threadIdx.x;
    int v = (n < N_NODES) ? deg[n] : 0;
    #pragma unroll
    for (int o = 1; o < 64; o <<= 1) v += __shfl_xor(v, o);
    int lane = threadIdx.x & 63, wv = threadIdx.x >> 6;
    if (lane == 0) ws[wv] = v;
    __syncthreads();
    if (threadIdx.x == 0) bsum[blockIdx.x] = ws[0] + ws[1] + ws[2] + ws[3];
}

// level 2: exclusive scan of the NBLK block sums (single tiny block)
__global__ __launch_bounds__(256) void k_bscan(const int* __restrict__ bsum,
                                               int* __restrict__ bbase){
    __shared__ int sp[256];
    int t = threadIdx.x;
    int v = (t < NBLK) ? bsum[t] : 0;
    sp[t] = v;
    __syncthreads();
    #pragma unroll
    for (int d = 1; d < 256; d <<= 1){
        int u = (t >= d) ? sp[t - d] : 0;
        __syncthreads();
        sp[t] += u;
        __syncthreads();
    }
    if (t < NBLK) bbase[t] = sp[t] - v;   // exclusive
}

// level 3: in-block exclusive scan + base -> ofs, cur=0, self-loop slot
__global__ __launch_bounds__(256) void k_apply(const int* __restrict__ deg,
                                               const int* __restrict__ bbase,
                                               int* __restrict__ ofs,
                                               int* __restrict__ cur,
                                               int* __restrict__ csr_src){
    __shared__ int sp[256];
    int t = threadIdx.x;
    int n = blockIdx.x * 256 + t;
    int v = (n < N_NODES) ? deg[n] : 0;
    sp[t] = v;
    __syncthreads();
    #pragma unroll
    for (int d = 1; d < 256; d <<= 1){
        int u = (t >= d) ? sp[t - d] : 0;
        __syncthreads();
        sp[t] += u;
        __syncthreads();
    }
    if (n < N_NODES){
        int o = bbase[blockIdx.x] + sp[t] - v;
        ofs[n] = o;
        cur[n] = 0;
        csr_src[o + v - 1] = n;           // self-loop in last slot
    }
}

__global__ void k_scatter(const int* __restrict__ ei, const int* __restrict__ ofs,
                          int* __restrict__ cur, int* __restrict__ csr_src){
    int e = blockIdx.x * 256 + threadIdx.x;
    if (e >= E_EDGES) return;
    int d = ei[E_EDGES + e];
    int p = atomicAdd(&cur[d], 1);
    csr_src[ofs[d] + p] = ei[e];
}

// ================= layer 1 GEMM (split-bf16 MFMA) =================
__global__ void k_wprep(const float* __restrict__ W1,
                        unsigned short* __restrict__ wfh,
                        unsigned short* __restrict__ wfl){
    int t = blockIdx.x * 256 + threadIdx.x;      // 4096 threads
    int lane = t & 63, nt = (t >> 6) & 3, ks = t >> 8;
    int c  = nt * 16 + (lane & 15);
    int k0 = ks * 32 + (lane >> 4) * 8;
    size_t base = ((size_t)(ks * 4 + nt) * 64 + lane) * 8;
    #pragma unroll
    for (int j = 0; j < 8; j++){
        short h, l;
        split1(W1[(size_t)(k0 + j) * C1 + c], h, l);
        wfh[base + j] = (unsigned short)h;
        wfl[base + j] = (unsigned short)l;
    }
}

__global__ __launch_bounds__(256) void k_gemm1(
        const float* __restrict__ x,
        const unsigned short* __restrict__ wfh,
        const unsigned short* __restrict__ wfl,
        float* __restrict__ h1, unsigned short* __restrict__ h1b){
    int lane = threadIdx.x & 63;
    int wv   = threadIdx.x >> 6;
    int row0 = blockIdx.x * 64 + wv * 16;

    int arow = row0 + (lane & 15);
    if (arow >= N_NODES) arow = N_NODES - 1;     // clamp (stores guarded)
    const float* xp = x + (size_t)arow * F_INF + (lane >> 4) * 8;

    f32x4 acc[4];
    #pragma unroll
    for (int nt = 0; nt < 4; nt++) acc[nt] = (f32x4){0.f, 0.f, 0.f, 0.f};

    for (int ks = 0; ks < 16; ks++){
        float4 va = *(const float4*)(xp + ks * 32);
        float4 vb = *(const float4*)(xp + ks * 32 + 4);
        short8 ah, al;
        {
            float v[8] = {va.x, va.y, va.z, va.w, vb.x, vb.y, vb.z, vb.w};
            #pragma unroll
            for (int j = 0; j < 8; j++){ short h, l; split1(v[j], h, l); ah[j] = h; al[j] = l; }
        }
        const unsigned short* bh0 = wfh + ((size_t)(ks * 4) * 64 + lane) * 8;
        const unsigned short* bl0 = wfl + ((size_t)(ks * 4) * 64 + lane) * 8;
        #pragma unroll
        for (int nt = 0; nt < 4; nt++){
            short8 bh = *(const short8*)(bh0 + (size_t)nt * 64 * 8);
            short8 bl = *(const short8*)(bl0 + (size_t)nt * 64 * 8);
            acc[nt] = __builtin_amdgcn_mfma_f32_16x16x32_bf16(ah, bh, acc[nt], 0, 0, 0);
            acc[nt] = __builtin_amdgcn_mfma_f32_16x16x32_bf16(ah, bl, acc[nt], 0, 0, 0);
            acc[nt] = __builtin_amdgcn_mfma_f32_16x16x32_bf16(al, bh, acc[nt], 0, 0, 0);
        }
    }

    // C/D layout: col = lane&15, row = (lane>>4)*4 + reg   [m89-verified]
    int g = lane >> 4, c = lane & 15;
    #pragma unroll
    for (int nt = 0; nt < 4; nt++){
        #pragma unroll
        for (int r = 0; r < 4; r++){
            int row = row0 + g * 4 + r;
            if (row < N_NODES){
                h1 [(size_t)row * C1 + nt * 16 + c] = acc[nt][r];
                h1b[(size_t)row * C1 + nt * 16 + c] = rne_bf16(acc[nt][r]);
            }
        }
    }
}

// ================= attention logits from h1 =================
__global__ void k_logits(const float* __restrict__ h1, const float* __restrict__ a1s,
                         const float* __restrict__ a1d,
                         float* __restrict__ als1, float* __restrict__ ald1){
    int t = blockIdx.x * 256 + threadIdx.x;
    if (t >= N_NODES * HEADS) return;
    int h = t & 7;
    const float* hp = h1 + (size_t)t * 8;
    float4 p = *(const float4*)(hp);
    float4 q = *(const float4*)(hp + 4);
    const float* as = a1s + h * 8;
    const float* ad = a1d + h * 8;
    float s = p.x*as[0] + p.y*as[1] + p.z*as[2] + p.w*as[3]
            + q.x*as[4] + q.y*as[5] + q.z*as[6] + q.w*as[7];
    float d = p.x*ad[0] + p.y*ad[1] + p.z*ad[2] + p.w*ad[3]
            + q.x*ad[4] + q.y*ad[5] + q.z*ad[6] + q.w*ad[7];
    als1[t] = s; ald1[t] = d;
}

// ================= layer1 aggregate + normalize + ELU + layer2 GEMM ========
// one wave per node; lane = feature; NO barriers, NO LDS.
// per 8-edge step: lane (j=lane&7, h=lane>>3) computes THE one exp for
// (edge j, head h); consumers broadcast via __shfl. 64 distinct exps/step.
__global__ __launch_bounds__(256) void k_agg1(
        const int* __restrict__ csr_src, const int* __restrict__ ofs,
        const int* __restrict__ deg,
        const float* __restrict__ als1, const float* __restrict__ ald1,
        const unsigned short* __restrict__ h1b,
        const float* __restrict__ b1, const float* __restrict__ W2,
        const float* __restrict__ a2s, const float* __restrict__ a2d,
        float* __restrict__ h2, float* __restrict__ als2, float* __restrict__ ald2){
    int lane = threadIdx.x & 63;
    int wv   = threadIdx.x >> 6;
    int n = blockIdx.x * 4 + wv;
    int h = lane >> 3;            // head for BOTH feature duty and exp duty
    int jm = lane & 7;            // exp duty: edge sub-index
    int start = ofs[n], dcount = deg[n];
    int end = start + dcount;
    float aldv = ald1[n * HEADS + h];
    float acc = 0.f, dsum = 0.f;
    for (int i = start; i < end; i += 8){
        // exp duty: one exp per lane
        int idm = i + jm;
        bool ok = idm < end;
        int svm = csr_src[ok ? idm : end - 1];
        float ev = leaky(als1[svm * HEADS + h] + aldv);
        float exval = ok ? __expf(ev) : 0.f;
        // uniform-address edge list for gather addresses
        int sv[8];
        #pragma unroll
        for (int j = 0; j < 8; j++){
            int id = i + j;
            sv[j] = csr_src[id < end ? id : end - 1];
        }
        int base = lane & 56;
        #pragma unroll
        for (int j = 0; j < 8; j++){
            float exj = __shfl(exval, base | j);
            float hv  = bf_to_f(h1b[(size_t)sv[j] * C1 + lane]);
            acc = fmaf(exj, hv, acc);
            dsum += exj;
        }
    }
    float v = acc / (dsum + 1e-16f) + b1[lane];
    float el = v > 0.f ? v : expm1f(v);
    // W2 GEMM via wave-wide shfl_xor tree: p[c] = sum_k el_k * W2[k][c]
    float p[NCLS];
    #pragma unroll
    for (int c = 0; c < NCLS; c++) p[c] = el * W2[lane * NCLS + c];
    #pragma unroll
    for (int o = 1; o < 64; o <<= 1){
        #pragma unroll
        for (int c = 0; c < NCLS; c++) p[c] += __shfl_xor(p[c], o);
    }
    if (lane == 0){
        float ps = 0.f, pd = 0.f;
        #pragma unroll
        for (int c = 0; c < NCLS; c++){
            h2[n * NCLS + c] = p[c];
            ps = fmaf(p[c], a2s[c], ps);
            pd = fmaf(p[c], a2d[c], pd);
        }
        als2[n] = ps; ald2[n] = pd;
    }
}

// ================= layer2 aggregate + log_softmax ==========================
// one wave per node; 8 groups x 8 lanes; group g walks edges g, g+8, ...
// c = lane&7: c<7 -> feature, c==7 -> denominator.
__global__ __launch_bounds__(256) void k_agg2(
        const int* __restrict__ csr_src, const int* __restrict__ ofs,
        const int* __restrict__ deg,
        const float* __restrict__ als2, const float* __restrict__ ald2,
        const float* __restrict__ h2, const float* __restrict__ b2,
        float* __restrict__ out){
    int lane = threadIdx.x & 63;
    int wv   = threadIdx.x >> 6;
    int n = blockIdx.x * 4 + wv;
    int c = lane & 7, g = lane >> 3;
    int start = ofs[n], dcount = deg[n];
    float aldv = ald2[n];
    float acc = 0.f;
    for (int i = g; i < dcount; i += 8){
        int s = csr_src[start + i];
        float ex = __expf(leaky(als2[s] + aldv));
        acc += (c < NCLS) ? ex * h2[s * NCLS + c] : ex;
    }
    acc += __shfl_xor(acc, 8); acc += __shfl_xor(acc, 16); acc += __shfl_xor(acc, 32);
    float den = __shfl(acc, lane | 7) + 1e-16f;
    float v = acc / den + b2[c < NCLS ? c : 0];
    float vm = (c < NCLS) ? v : -INFINITY;
    vm = fmaxf(vm, __shfl_xor(vm, 1));
    vm = fmaxf(vm, __shfl_xor(vm, 2));
    vm = fmaxf(vm, __shfl_xor(vm, 4));
    float ev = (c < NCLS) ? __expf(v - vm) : 0.f;
    ev += __shfl_xor(ev, 1); ev += __shfl_xor(ev, 2); ev += __shfl_xor(ev, 4);
    float lse = vm + logf(ev);
    if (g == 0 && c < NCLS) out[n * NCLS + c] = v - lse;
}

extern "C" void kernel_launch(void* const* d_in, const int* in_sizes, int n_in,
                              void* d_out, int out_size, void* d_ws, size_t ws_size,
                              hipStream_t stream){
    const float* x    = (const float*)d_in[0];
    const int*   ei   = (const int*)  d_in[1];
    const float* W1   = (const float*)d_in[2];
    const float* a1s  = (const float*)d_in[3];
    const float* a1d  = (const float*)d_in[4];
    const float* b1   = (const float*)d_in[5];
    const float* W2   = (const float*)d_in[6];
    const float* a2s  = (const float*)d_in[7];
    const float* a2d  = (const float*)d_in[8];
    const float* b2   = (const float*)d_in[9];
    float* out = (float*)d_out;

    float* w = (float*)d_ws;
    float*    h1   = w;              w += (size_t)N_NODES * C1;
    unsigned short* h1b = (unsigned short*)w;  w += (size_t)N_NODES * C1 / 2;
    float*    als1 = w;              w += N_NODES * HEADS;
    float*    ald1 = w;              w += N_NODES * HEADS;
    float*    h2   = w;              w += N_NODES * NCLS;
    float*    als2 = w;              w += N_NODES;
    float*    ald2 = w;              w += N_NODES;
    unsigned short* wfh = (unsigned short*)w;  w += (16 * 4 * 64 * 8) / 2;
    unsigned short* wfl = (unsigned short*)w;  w += (16 * 4 * 64 * 8) / 2;
    int* deg     = (int*)w;          w += N_NODES;
    int* cur     = (int*)w;          w += N_NODES;
    int* ofs     = (int*)w;          w += N_NODES;
    int* bsum    = (int*)w;          w += 256;
    int* bbase   = (int*)w;          w += 256;
    int* csr_src = (int*)w;          w += ETOT;

    k_zero   <<<NBLK, 256, 0, stream>>>(deg);
    k_hist   <<<(E_EDGES + 255) / 256, 256, 0, stream>>>(ei, deg);
    k_bsum   <<<NBLK, 256, 0, stream>>>(deg, bsum);
    k_bscan  <<<1, 256, 0, stream>>>(bsum, bbase);
    k_apply  <<<NBLK, 256, 0, stream>>>(deg, bbase, ofs, cur, csr_src);
    k_scatter<<<(E_EDGES + 255) / 256, 256, 0, stream>>>(ei, ofs, cur, csr_src);
    k_wprep  <<<16, 256, 0, stream>>>(W1, wfh, wfl);
    k_gemm1  <<<(N_NODES + 63) / 64, 256, 0, stream>>>(x, wfh, wfl, h1, h1b);
    k_logits <<<(N_NODES * HEADS + 255) / 256, 256, 0, stream>>>(h1, a1s, a1d, als1, ald1);
    k_agg1   <<<N_NODES / 4, 256, 0, stream>>>(csr_src, ofs, deg, als1, ald1, h1b,
                                               b1, W2, a2s, a2d, h2, als2, ald2);
    k_agg2   <<<N_NODES / 4, 256, 0, stream>>>(csr_src, ofs, deg, als2, ald2, h2, b2, out);
}

// Round 12
// 205.317 us; speedup vs baseline: 4.4695x; 1.0403x over previous
//
#include <hip/hip_runtime.h>
#include <math.h>

#define N_NODES 50000
#define E_EDGES 800000
#define ETOT    850000   // E + N self loops
#define F_INF   512
#define HEADS   8
#define C1      64       // HEADS*HID
#define NCLS    7
#define SLOPE   0.2f
#define NBLK    196      // ceil(N_NODES/256)

typedef __attribute__((ext_vector_type(8))) short short8;
typedef __attribute__((ext_vector_type(4))) float f32x4;

__device__ __forceinline__ float leaky(float x){ return x > 0.f ? x : SLOPE * x; }

// split f32 -> bf16 hi (truncated) + bf16 lo (RNE of residual)
__device__ __forceinline__ void split1(float v, short& h, short& l){
    unsigned u = __float_as_uint(v);
    unsigned hw = u >> 16;
    float fh = __uint_as_float(hw << 16);
    float r  = v - fh;
    unsigned ul = __float_as_uint(r);
    unsigned lw = (ul + 0x7fffu + ((ul >> 16) & 1u)) >> 16;
    h = (short)hw; l = (short)lw;
}

__device__ __forceinline__ unsigned short rne_bf16(float v){
    unsigned u = __float_as_uint(v);
    return (unsigned short)((u + 0x7fffu + ((u >> 16) & 1u)) >> 16);
}
__device__ __forceinline__ float bf_to_f(unsigned short us){
    return __uint_as_float((unsigned)us << 16);
}

// ================= CSR build =================
__global__ void k_zero(int* deg){
    int n = blockIdx.x * 256 + threadIdx.x;
    if (n < N_NODES) deg[n] = 1;          // self loop
}

__global__ void k_hist(const int* __restrict__ ei, int* __restrict__ deg){
    int e = blockIdx.x * 256 + threadIdx.x;
    if (e < E_EDGES) atomicAdd(&deg[ei[E_EDGES + e]], 1);
}

// level 1: per-block sums of deg
__global__ __launch_bounds__(256) void k_bsum(const int* __restrict__ deg,
                                              int* __restrict__ bsum){
    __shared__ int ws[4];
    int n = blockIdx.x * 256 + threadIdx.x;
    int v = (n < N_NODES) ? deg[n] : 0;
    #pragma unroll
    for (int o = 1; o < 64; o <<= 1) v += __shfl_xor(v, o);
    int lane = threadIdx.x & 63, wv = threadIdx.x >> 6;
    if (lane == 0) ws[wv] = v;
    __syncthreads();
    if (threadIdx.x == 0) bsum[blockIdx.x] = ws[0] + ws[1] + ws[2] + ws[3];
}

// level 2: exclusive scan of the NBLK block sums (single tiny block)
__global__ __launch_bounds__(256) void k_bscan(const int* __restrict__ bsum,
                                               int* __restrict__ bbase){
    __shared__ int sp[256];
    int t = threadIdx.x;
    int v = (t < NBLK) ? bsum[t] : 0;
    sp[t] = v;
    __syncthreads();
    #pragma unroll
    for (int d = 1; d < 256; d <<= 1){
        int u = (t >= d) ? sp[t - d] : 0;
        __syncthreads();
        sp[t] += u;
        __syncthreads();
    }
    if (t < NBLK) bbase[t] = sp[t] - v;   // exclusive
}

// level 3: in-block exclusive scan + base -> ofs, cur=0, self-loop slot
__global__ __launch_bounds__(256) void k_apply(const int* __restrict__ deg,
                                               const int* __restrict__ bbase,
                                               int* __restrict__ ofs,
                                               int* __restrict__ cur,
                                               int* __restrict__ csr_src){
    __shared__ int sp[256];
    int t = threadIdx.x;
    int n = blockIdx.x * 256 + t;
    int v = (n < N_NODES) ? deg[n] : 0;
    sp[t] = v;
    __syncthreads();
    #pragma unroll
    for (int d = 1; d < 256; d <<= 1){
        int u = (t >= d) ? sp[t - d] : 0;
        __syncthreads();
        sp[t] += u;
        __syncthreads();
    }
    if (n < N_NODES){
        int o = bbase[blockIdx.x] + sp[t] - v;
        ofs[n] = o;
        cur[n] = 0;
        csr_src[o + v - 1] = n;           // self-loop in last slot
    }
}

__global__ void k_scatter(const int* __restrict__ ei, const int* __restrict__ ofs,
                          int* __restrict__ cur, int* __restrict__ csr_src){
    int e = blockIdx.x * 256 + threadIdx.x;
    if (e >= E_EDGES) return;
    int d = ei[E_EDGES + e];
    int p = atomicAdd(&cur[d], 1);
    csr_src[ofs[d] + p] = ei[e];
}

// ================= layer 1 GEMM (bf16 MFMA, B split hi/lo) =================
__global__ void k_wprep(const float* __restrict__ W1,
                        unsigned short* __restrict__ wfh,
                        unsigned short* __restrict__ wfl){
    int t = blockIdx.x * 256 + threadIdx.x;      // 4096 threads
    int lane = t & 63, nt = (t >> 6) & 3, ks = t >> 8;
    int c  = nt * 16 + (lane & 15);
    int k0 = ks * 32 + (lane >> 4) * 8;
    size_t base = ((size_t)(ks * 4 + nt) * 64 + lane) * 8;
    #pragma unroll
    for (int j = 0; j < 8; j++){
        short h, l;
        split1(W1[(size_t)(k0 + j) * C1 + c], h, l);
        wfh[base + j] = (unsigned short)h;
        wfl[base + j] = (unsigned short)l;
    }
}

// 1-deep software-pipelined; A = RNE bf16; fused logits epilogue.
__global__ __launch_bounds__(256) void k_gemm1(
        const float* __restrict__ x,
        const unsigned short* __restrict__ wfh,
        const unsigned short* __restrict__ wfl,
        const float* __restrict__ a1s, const float* __restrict__ a1d,
        unsigned short* __restrict__ h1b,
        float* __restrict__ als1, float* __restrict__ ald1){
    int lane = threadIdx.x & 63;
    int wv   = threadIdx.x >> 6;
    int row0 = blockIdx.x * 64 + wv * 16;

    int arow = row0 + (lane & 15);
    if (arow >= N_NODES) arow = N_NODES - 1;     // clamp (stores guarded)
    const float* xp = x + (size_t)arow * F_INF + (lane >> 4) * 8;
    const unsigned short* bhp = wfh + (size_t)lane * 8;
    const unsigned short* blp = wfl + (size_t)lane * 8;

    f32x4 acc[4];
    #pragma unroll
    for (int nt = 0; nt < 4; nt++) acc[nt] = (f32x4){0.f, 0.f, 0.f, 0.f};

    // preload ks = 0
    float4 va = *(const float4*)(xp);
    float4 vb = *(const float4*)(xp + 4);
    short8 bh[4], bl[4];
    #pragma unroll
    for (int nt = 0; nt < 4; nt++){
        bh[nt] = *(const short8*)(bhp + (size_t)nt * 64 * 8);
        bl[nt] = *(const short8*)(blp + (size_t)nt * 64 * 8);
    }

#define GEMM_STEP                                                         \
    {                                                                     \
        short8 ah;                                                        \
        float v_[8] = {va.x, va.y, va.z, va.w, vb.x, vb.y, vb.z, vb.w};   \
        _Pragma("unroll")                                                 \
        for (int j = 0; j < 8; j++) ah[j] = (short)rne_bf16(v_[j]);       \
        _Pragma("unroll")                                                 \
        for (int nt = 0; nt < 4; nt++){                                   \
            acc[nt] = __builtin_amdgcn_mfma_f32_16x16x32_bf16(ah, bh[nt], acc[nt], 0, 0, 0); \
            acc[nt] = __builtin_amdgcn_mfma_f32_16x16x32_bf16(ah, bl[nt], acc[nt], 0, 0, 0); \
        }                                                                 \
    }

    #pragma unroll 1
    for (int ks = 0; ks < 15; ks++){
        // issue next-step loads first (latency hides under current MFMAs)
        float4 van = *(const float4*)(xp + (ks + 1) * 32);
        float4 vbn = *(const float4*)(xp + (ks + 1) * 32 + 4);
        short8 bhn[4], bln[4];
        #pragma unroll
        for (int nt = 0; nt < 4; nt++){
            bhn[nt] = *(const short8*)(bhp + (size_t)((ks + 1) * 4 + nt) * 64 * 8);
            bln[nt] = *(const short8*)(blp + (size_t)((ks + 1) * 4 + nt) * 64 * 8);
        }
        GEMM_STEP
        va = van; vb = vbn;
        #pragma unroll
        for (int nt = 0; nt < 4; nt++){ bh[nt] = bhn[nt]; bl[nt] = bln[nt]; }
    }
    GEMM_STEP
#undef GEMM_STEP

    // C/D layout: col = lane&15, row = (lane>>4)*4 + reg   [m89-verified]
    int g = lane >> 4, c = lane & 15;
    #pragma unroll
    for (int nt = 0; nt < 4; nt++){
        #pragma unroll
        for (int r = 0; r < 4; r++){
            int row = row0 + g * 4 + r;
            if (row < N_NODES)
                h1b[(size_t)row * C1 + nt * 16 + c] = rne_bf16(acc[nt][r]);
        }
    }

    // fused attention logits: head of col (nt*16+c) = nt*2 + (c>>3)
    float s_[4][4], d_[4][4];
    #pragma unroll
    for (int nt = 0; nt < 4; nt++){
        float as = a1s[nt * 16 + c], ad = a1d[nt * 16 + c];
        #pragma unroll
        for (int r = 0; r < 4; r++){
            float vs = acc[nt][r] * as;
            float vd = acc[nt][r] * ad;
            vs += __shfl_xor(vs, 1); vs += __shfl_xor(vs, 2); vs += __shfl_xor(vs, 4);
            vd += __shfl_xor(vd, 1); vd += __shfl_xor(vd, 2); vd += __shfl_xor(vd, 4);
            s_[nt][r] = vs; d_[nt][r] = vd;
        }
    }
    if ((lane & 7) == 0){
        int b = c >> 3;                  // c in {0, 8}
        #pragma unroll
        for (int nt = 0; nt < 4; nt++){
            int h = nt * 2 + b;
            #pragma unroll
            for (int r = 0; r < 4; r++){
                int row = row0 + g * 4 + r;
                if (row < N_NODES){
                    als1[row * HEADS + h] = s_[nt][r];
                    ald1[row * HEADS + h] = d_[nt][r];
                }
            }
        }
    }
}

// ================= layer1 aggregate + normalize + ELU + layer2 GEMM ========
// one wave per node; lane = feature; NO barriers, NO LDS.
// per 8-edge step: lane (j=lane&7, h=lane>>3) computes THE one exp for
// (edge j, head h); consumers broadcast via __shfl. 64 distinct exps/step.
__global__ __launch_bounds__(256) void k_agg1(
        const int* __restrict__ csr_src, const int* __restrict__ ofs,
        const int* __restrict__ deg,
        const float* __restrict__ als1, const float* __restrict__ ald1,
        const unsigned short* __restrict__ h1b,
        const float* __restrict__ b1, const float* __restrict__ W2,
        const float* __restrict__ a2s, const float* __restrict__ a2d,
        float* __restrict__ h2, float* __restrict__ als2, float* __restrict__ ald2){
    int lane = threadIdx.x & 63;
    int wv   = threadIdx.x >> 6;
    int n = blockIdx.x * 4 + wv;
    int h = lane >> 3;            // head for BOTH feature duty and exp duty
    int jm = lane & 7;            // exp duty: edge sub-index
    int start = ofs[n], dcount = deg[n];
    int end = start + dcount;
    float aldv = ald1[n * HEADS + h];
    float acc = 0.f, dsum = 0.f;
    for (int i = start; i < end; i += 8){
        // exp duty: one exp per lane
        int idm = i + jm;
        bool ok = idm < end;
        int svm = csr_src[ok ? idm : end - 1];
        float ev = leaky(als1[svm * HEADS + h] + aldv);
        float exval = ok ? __expf(ev) : 0.f;
        // uniform-address edge list for gather addresses
        int sv[8];
        #pragma unroll
        for (int j = 0; j < 8; j++){
            int id = i + j;
            sv[j] = csr_src[id < end ? id : end - 1];
        }
        int base = lane & 56;
        #pragma unroll
        for (int j = 0; j < 8; j++){
            float exj = __shfl(exval, base | j);
            float hv  = bf_to_f(h1b[(size_t)sv[j] * C1 + lane]);
            acc = fmaf(exj, hv, acc);
            dsum += exj;
        }
    }
    float v = acc / (dsum + 1e-16f) + b1[lane];
    float el = v > 0.f ? v : expm1f(v);
    // W2 GEMM via wave-wide shfl_xor tree: p[c] = sum_k el_k * W2[k][c]
    float p[NCLS];
    #pragma unroll
    for (int c = 0; c < NCLS; c++) p[c] = el * W2[lane * NCLS + c];
    #pragma unroll
    for (int o = 1; o < 64; o <<= 1){
        #pragma unroll
        for (int c = 0; c < NCLS; c++) p[c] += __shfl_xor(p[c], o);
    }
    if (lane == 0){
        float ps = 0.f, pd = 0.f;
        #pragma unroll
        for (int c = 0; c < NCLS; c++){
            h2[n * NCLS + c] = p[c];
            ps = fmaf(p[c], a2s[c], ps);
            pd = fmaf(p[c], a2d[c], pd);
        }
        als2[n] = ps; ald2[n] = pd;
    }
}

// ================= layer2 aggregate + log_softmax ==========================
// one wave per node; 8 groups x 8 lanes; group g walks edges g, g+8, ...
// c = lane&7: c<7 -> feature, c==7 -> denominator.
__global__ __launch_bounds__(256) void k_agg2(
        const int* __restrict__ csr_src, const int* __restrict__ ofs,
        const int* __restrict__ deg,
        const float* __restrict__ als2, const float* __restrict__ ald2,
        const float* __restrict__ h2, const float* __restrict__ b2,
        float* __restrict__ out){
    int lane = threadIdx.x & 63;
    int wv   = threadIdx.x >> 6;
    int n = blockIdx.x * 4 + wv;
    int c = lane & 7, g = lane >> 3;
    int start = ofs[n], dcount = deg[n];
    float aldv = ald2[n];
    float acc = 0.f;
    for (int i = g; i < dcount; i += 8){
        int s = csr_src[start + i];
        float ex = __expf(leaky(als2[s] + aldv));
        acc += (c < NCLS) ? ex * h2[s * NCLS + c] : ex;
    }
    acc += __shfl_xor(acc, 8); acc += __shfl_xor(acc, 16); acc += __shfl_xor(acc, 32);
    float den = __shfl(acc, lane | 7) + 1e-16f;
    float v = acc / den + b2[c < NCLS ? c : 0];
    float vm = (c < NCLS) ? v : -INFINITY;
    vm = fmaxf(vm, __shfl_xor(vm, 1));
    vm = fmaxf(vm, __shfl_xor(vm, 2));
    vm = fmaxf(vm, __shfl_xor(vm, 4));
    float ev = (c < NCLS) ? __expf(v - vm) : 0.f;
    ev += __shfl_xor(ev, 1); ev += __shfl_xor(ev, 2); ev += __shfl_xor(ev, 4);
    float lse = vm + logf(ev);
    if (g == 0 && c < NCLS) out[n * NCLS + c] = v - lse;
}

extern "C" void kernel_launch(void* const* d_in, const int* in_sizes, int n_in,
                              void* d_out, int out_size, void* d_ws, size_t ws_size,
                              hipStream_t stream){
    const float* x    = (const float*)d_in[0];
    const int*   ei   = (const int*)  d_in[1];
    const float* W1   = (const float*)d_in[2];
    const float* a1s  = (const float*)d_in[3];
    const float* a1d  = (const float*)d_in[4];
    const float* b1   = (const float*)d_in[5];
    const float* W2   = (const float*)d_in[6];
    const float* a2s  = (const float*)d_in[7];
    const float* a2d  = (const float*)d_in[8];
    const float* b2   = (const float*)d_in[9];
    float* out = (float*)d_out;

    float* w = (float*)d_ws;
    unsigned short* h1b = (unsigned short*)w;  w += (size_t)N_NODES * C1 / 2;
    float*    als1 = w;              w += N_NODES * HEADS;
    float*    ald1 = w;              w += N_NODES * HEADS;
    float*    h2   = w;              w += N_NODES * NCLS;
    float*    als2 = w;              w += N_NODES;
    float*    ald2 = w;              w += N_NODES;
    unsigned short* wfh = (unsigned short*)w;  w += (16 * 4 * 64 * 8) / 2;
    unsigned short* wfl = (unsigned short*)w;  w += (16 * 4 * 64 * 8) / 2;
    int* deg     = (int*)w;          w += N_NODES;
    int* cur     = (int*)w;          w += N_NODES;
    int* ofs     = (int*)w;          w += N_NODES;
    int* bsum    = (int*)w;          w += 256;
    int* bbase   = (int*)w;          w += 256;
    int* csr_src = (int*)w;          w += ETOT;

    k_zero   <<<NBLK, 256, 0, stream>>>(deg);
    k_hist   <<<(E_EDGES + 255) / 256, 256, 0, stream>>>(ei, deg);
    k_bsum   <<<NBLK, 256, 0, stream>>>(deg, bsum);
    k_bscan  <<<1, 256, 0, stream>>>(bsum, bbase);
    k_apply  <<<NBLK, 256, 0, stream>>>(deg, bbase, ofs, cur, csr_src);
    k_scatter<<<(E_EDGES + 255) / 256, 256, 0, stream>>>(ei, ofs, cur, csr_src);
    k_wprep  <<<16, 256, 0, stream>>>(W1, wfh, wfl);
    k_gemm1  <<<(N_NODES + 63) / 64, 256, 0, stream>>>(x, wfh, wfl, a1s, a1d,
                                                       h1b, als1, ald1);
    k_agg1   <<<N_NODES / 4, 256, 0, stream>>>(csr_src, ofs, deg, als1, ald1, h1b,
                                               b1, W2, a2s, a2d, h2, als2, ald2);
    k_agg2   <<<N_NODES / 4, 256, 0, stream>>>(csr_src, ofs, deg, als2, ald2, h2, b2, out);
}

// Round 13
// 201.557 us; speedup vs baseline: 4.5529x; 1.0187x over previous
//
#include <hip/hip_runtime.h>
#include <math.h>

#define N_NODES 50000
#define E_EDGES 800000
#define ETOT    850000   // E + N self loops
#define F_INF   512
#define HEADS   8
#define C1      64       // HEADS*HID
#define NCLS    7
#define SLOPE   0.2f
#define NBLK    196      // ceil(N_NODES/256)

typedef __attribute__((ext_vector_type(8))) short short8;
typedef __attribute__((ext_vector_type(4))) float f32x4;

__device__ __forceinline__ float leaky(float x){ return x > 0.f ? x : SLOPE * x; }

// split f32 -> bf16 hi (truncated) + bf16 lo (RNE of residual)
__device__ __forceinline__ void split1(float v, short& h, short& l){
    unsigned u = __float_as_uint(v);
    unsigned hw = u >> 16;
    float fh = __uint_as_float(hw << 16);
    float r  = v - fh;
    unsigned ul = __float_as_uint(r);
    unsigned lw = (ul + 0x7fffu + ((ul >> 16) & 1u)) >> 16;
    h = (short)hw; l = (short)lw;
}

__device__ __forceinline__ unsigned short rne_bf16(float v){
    unsigned u = __float_as_uint(v);
    return (unsigned short)((u + 0x7fffu + ((u >> 16) & 1u)) >> 16);
}
__device__ __forceinline__ float bf_to_f(unsigned short us){
    return __uint_as_float((unsigned)us << 16);
}

// ================= CSR build =================
__global__ void k_zero(int* deg){
    int n = blockIdx.x * 256 + threadIdx.x;
    if (n < N_NODES) deg[n] = 1;          // self loop
}

__global__ void k_hist(const int* __restrict__ ei, int* __restrict__ deg){
    int e = blockIdx.x * 256 + threadIdx.x;
    if (e < E_EDGES) atomicAdd(&deg[ei[E_EDGES + e]], 1);
}

// level 1: per-block sums of deg
__global__ __launch_bounds__(256) void k_bsum(const int* __restrict__ deg,
                                              int* __restrict__ bsum){
    __shared__ int ws[4];
    int n = blockIdx.x * 256 + threadIdx.x;
    int v = (n < N_NODES) ? deg[n] : 0;
    #pragma unroll
    for (int o = 1; o < 64; o <<= 1) v += __shfl_xor(v, o);
    int lane = threadIdx.x & 63, wv = threadIdx.x >> 6;
    if (lane == 0) ws[wv] = v;
    __syncthreads();
    if (threadIdx.x == 0) bsum[blockIdx.x] = ws[0] + ws[1] + ws[2] + ws[3];
}

// level 2: exclusive scan of the NBLK block sums (single tiny block)
__global__ __launch_bounds__(256) void k_bscan(const int* __restrict__ bsum,
                                               int* __restrict__ bbase){
    __shared__ int sp[256];
    int t = threadIdx.x;
    int v = (t < NBLK) ? bsum[t] : 0;
    sp[t] = v;
    __syncthreads();
    #pragma unroll
    for (int d = 1; d < 256; d <<= 1){
        int u = (t >= d) ? sp[t - d] : 0;
        __syncthreads();
        sp[t] += u;
        __syncthreads();
    }
    if (t < NBLK) bbase[t] = sp[t] - v;   // exclusive
}

// level 3: in-block exclusive scan + base -> ofs, cur=0, self-loop slot
__global__ __launch_bounds__(256) void k_apply(const int* __restrict__ deg,
                                               const int* __restrict__ bbase,
                                               int* __restrict__ ofs,
                                               int* __restrict__ cur,
                                               int* __restrict__ csr_src){
    __shared__ int sp[256];
    int t = threadIdx.x;
    int n = blockIdx.x * 256 + t;
    int v = (n < N_NODES) ? deg[n] : 0;
    sp[t] = v;
    __syncthreads();
    #pragma unroll
    for (int d = 1; d < 256; d <<= 1){
        int u = (t >= d) ? sp[t - d] : 0;
        __syncthreads();
        sp[t] += u;
        __syncthreads();
    }
    if (n < N_NODES){
        int o = bbase[blockIdx.x] + sp[t] - v;
        ofs[n] = o;
        cur[n] = 0;
        csr_src[o + v - 1] = n;           // self-loop in last slot
    }
}

__global__ void k_scatter(const int* __restrict__ ei, const int* __restrict__ ofs,
                          int* __restrict__ cur, int* __restrict__ csr_src){
    int e = blockIdx.x * 256 + threadIdx.x;
    if (e >= E_EDGES) return;
    int d = ei[E_EDGES + e];
    int p = atomicAdd(&cur[d], 1);
    csr_src[ofs[d] + p] = ei[e];
}

// ================= layer 1 GEMM (bf16 MFMA, B split hi/lo) =================
__global__ void k_wprep(const float* __restrict__ W1,
                        unsigned short* __restrict__ wfh,
                        unsigned short* __restrict__ wfl){
    int t = blockIdx.x * 256 + threadIdx.x;      // 4096 threads
    int lane = t & 63, nt = (t >> 6) & 3, ks = t >> 8;
    int c  = nt * 16 + (lane & 15);
    int k0 = ks * 32 + (lane >> 4) * 8;
    size_t base = ((size_t)(ks * 4 + nt) * 64 + lane) * 8;
    #pragma unroll
    for (int j = 0; j < 8; j++){
        short h, l;
        split1(W1[(size_t)(k0 + j) * C1 + c], h, l);
        wfh[base + j] = (unsigned short)h;
        wfl[base + j] = (unsigned short)l;
    }
}

// copies 8192 B (one superstep = 2 K-steps of fragments) into LDS
__device__ __forceinline__ void stage_b(const unsigned short* __restrict__ src,
                                        unsigned short* dst, int wv, int lane){
    #pragma unroll
    for (int i = 0; i < 2; i++){
        int off = i * 4096 + wv * 1024 + lane * 16;   // bytes
        __builtin_amdgcn_global_load_lds(
            (const __attribute__((address_space(1))) void*)((const char*)src + off),
            (__attribute__((address_space(3))) void*)((char*)dst + off),
            16, 0, 0);
    }
}

// LDS-staged B (shared by 4 waves), async double-buffer; A = RNE bf16;
// fused logits epilogue.
__global__ __launch_bounds__(256) void k_gemm1(
        const float* __restrict__ x,
        const unsigned short* __restrict__ wfh,
        const unsigned short* __restrict__ wfl,
        const float* __restrict__ a1s, const float* __restrict__ a1d,
        unsigned short* __restrict__ h1b,
        float* __restrict__ als1, float* __restrict__ ald1){
    __shared__ unsigned short sh[2][2][4096];   // [buf][hi/lo][2 ksteps x 2048]
    int lane = threadIdx.x & 63;
    int wv   = threadIdx.x >> 6;
    int row0 = blockIdx.x * 64 + wv * 16;

    int arow = row0 + (lane & 15);
    if (arow >= N_NODES) arow = N_NODES - 1;     // clamp (stores guarded)
    const float* xp = x + (size_t)arow * F_INF + (lane >> 4) * 8;

    f32x4 acc[4];
    #pragma unroll
    for (int nt = 0; nt < 4; nt++) acc[nt] = (f32x4){0.f, 0.f, 0.f, 0.f};

    stage_b(wfh, &sh[0][0][0], wv, lane);
    stage_b(wfl, &sh[0][1][0], wv, lane);
    __syncthreads();

    #pragma unroll 1
    for (int ss = 0; ss < 8; ss++){
        int buf = ss & 1;
        if (ss < 7){
            stage_b(wfh + (ss + 1) * 4096, &sh[buf ^ 1][0][0], wv, lane);
            stage_b(wfl + (ss + 1) * 4096, &sh[buf ^ 1][1][0], wv, lane);
        }
        // load A for both sub-steps early (independent, hides under MFMA)
        float4 va0 = *(const float4*)(xp + (ss * 2 + 0) * 32);
        float4 vb0 = *(const float4*)(xp + (ss * 2 + 0) * 32 + 4);
        float4 va1 = *(const float4*)(xp + (ss * 2 + 1) * 32);
        float4 vb1 = *(const float4*)(xp + (ss * 2 + 1) * 32 + 4);
        #pragma unroll
        for (int sub = 0; sub < 2; sub++){
            float4 va = sub ? va1 : va0;
            float4 vb = sub ? vb1 : vb0;
            short8 ah;
            {
                float v_[8] = {va.x, va.y, va.z, va.w, vb.x, vb.y, vb.z, vb.w};
                #pragma unroll
                for (int j = 0; j < 8; j++) ah[j] = (short)rne_bf16(v_[j]);
            }
            const unsigned short* bhq = &sh[buf][0][sub * 2048 + lane * 8];
            const unsigned short* blq = &sh[buf][1][sub * 2048 + lane * 8];
            #pragma unroll
            for (int nt = 0; nt < 4; nt++){
                short8 bh = *(const short8*)(bhq + nt * 512);
                short8 bl = *(const short8*)(blq + nt * 512);
                acc[nt] = __builtin_amdgcn_mfma_f32_16x16x32_bf16(ah, bh, acc[nt], 0, 0, 0);
                acc[nt] = __builtin_amdgcn_mfma_f32_16x16x32_bf16(ah, bl, acc[nt], 0, 0, 0);
            }
        }
        __syncthreads();   // staging of ss+1 complete; all waves done with buf
    }

    // C/D layout: col = lane&15, row = (lane>>4)*4 + reg   [m89-verified]
    int g = lane >> 4, c = lane & 15;
    #pragma unroll
    for (int nt = 0; nt < 4; nt++){
        #pragma unroll
        for (int r = 0; r < 4; r++){
            int row = row0 + g * 4 + r;
            if (row < N_NODES)
                h1b[(size_t)row * C1 + nt * 16 + c] = rne_bf16(acc[nt][r]);
        }
    }

    // fused attention logits: head of col (nt*16+c) = nt*2 + (c>>3)
    float s_[4][4], d_[4][4];
    #pragma unroll
    for (int nt = 0; nt < 4; nt++){
        float as = a1s[nt * 16 + c], ad = a1d[nt * 16 + c];
        #pragma unroll
        for (int r = 0; r < 4; r++){
            float vs = acc[nt][r] * as;
            float vd = acc[nt][r] * ad;
            vs += __shfl_xor(vs, 1); vs += __shfl_xor(vs, 2); vs += __shfl_xor(vs, 4);
            vd += __shfl_xor(vd, 1); vd += __shfl_xor(vd, 2); vd += __shfl_xor(vd, 4);
            s_[nt][r] = vs; d_[nt][r] = vd;
        }
    }
    if ((lane & 7) == 0){
        int b = c >> 3;                  // c in {0, 8}
        #pragma unroll
        for (int nt = 0; nt < 4; nt++){
            int h = nt * 2 + b;
            #pragma unroll
            for (int r = 0; r < 4; r++){
                int row = row0 + g * 4 + r;
                if (row < N_NODES){
                    als1[row * HEADS + h] = s_[nt][r];
                    ald1[row * HEADS + h] = d_[nt][r];
                }
            }
        }
    }
}

// ================= layer1 aggregate + normalize + ELU + layer2 GEMM ========
// one wave per node; lane = feature; NO barriers, NO LDS.
// per 8-edge step: lane (j=lane&7, h=lane>>3) computes THE one exp for
// (edge j, head h); consumers broadcast via __shfl. 64 distinct exps/step.
__global__ __launch_bounds__(256) void k_agg1(
        const int* __restrict__ csr_src, const int* __restrict__ ofs,
        const int* __restrict__ deg,
        const float* __restrict__ als1, const float* __restrict__ ald1,
        const unsigned short* __restrict__ h1b,
        const float* __restrict__ b1, const float* __restrict__ W2,
        const float* __restrict__ a2s, const float* __restrict__ a2d,
        float* __restrict__ h2, float* __restrict__ als2, float* __restrict__ ald2){
    int lane = threadIdx.x & 63;
    int wv   = threadIdx.x >> 6;
    int n = blockIdx.x * 4 + wv;
    int h = lane >> 3;            // head for BOTH feature duty and exp duty
    int jm = lane & 7;            // exp duty: edge sub-index
    int start = ofs[n], dcount = deg[n];
    int end = start + dcount;
    float aldv = ald1[n * HEADS + h];
    float acc = 0.f, dsum = 0.f;
    for (int i = start; i < end; i += 8){
        // exp duty: one exp per lane
        int idm = i + jm;
        bool ok = idm < end;
        int svm = csr_src[ok ? idm : end - 1];
        float ev = leaky(als1[svm * HEADS + h] + aldv);
        float exval = ok ? __expf(ev) : 0.f;
        // uniform-address edge list for gather addresses
        int sv[8];
        #pragma unroll
        for (int j = 0; j < 8; j++){
            int id = i + j;
            sv[j] = csr_src[id < end ? id : end - 1];
        }
        int base = lane & 56;
        #pragma unroll
        for (int j = 0; j < 8; j++){
            float exj = __shfl(exval, base | j);
            float hv  = bf_to_f(h1b[(size_t)sv[j] * C1 + lane]);
            acc = fmaf(exj, hv, acc);
            dsum += exj;
        }
    }
    float v = acc / (dsum + 1e-16f) + b1[lane];
    float el = v > 0.f ? v : expm1f(v);
    // W2 GEMM via wave-wide shfl_xor tree: p[c] = sum_k el_k * W2[k][c]
    float p[NCLS];
    #pragma unroll
    for (int c = 0; c < NCLS; c++) p[c] = el * W2[lane * NCLS + c];
    #pragma unroll
    for (int o = 1; o < 64; o <<= 1){
        #pragma unroll
        for (int c = 0; c < NCLS; c++) p[c] += __shfl_xor(p[c], o);
    }
    if (lane == 0){
        float ps = 0.f, pd = 0.f;
        #pragma unroll
        for (int c = 0; c < NCLS; c++){
            h2[n * NCLS + c] = p[c];
            ps = fmaf(p[c], a2s[c], ps);
            pd = fmaf(p[c], a2d[c], pd);
        }
        als2[n] = ps; ald2[n] = pd;
    }
}

// ================= layer2 aggregate + log_softmax ==========================
// one wave per node; 8 groups x 8 lanes; group g walks edges g, g+8, ...
// c = lane&7: c<7 -> feature, c==7 -> denominator.
__global__ __launch_bounds__(256) void k_agg2(
        const int* __restrict__ csr_src, const int* __restrict__ ofs,
        const int* __restrict__ deg,
        const float* __restrict__ als2, const float* __restrict__ ald2,
        const float* __restrict__ h2, const float* __restrict__ b2,
        float* __restrict__ out){
    int lane = threadIdx.x & 63;
    int wv   = threadIdx.x >> 6;
    int n = blockIdx.x * 4 + wv;
    int c = lane & 7, g = lane >> 3;
    int start = ofs[n], dcount = deg[n];
    float aldv = ald2[n];
    float acc = 0.f;
    for (int i = g; i < dcount; i += 8){
        int s = csr_src[start + i];
        float ex = __expf(leaky(als2[s] + aldv));
        acc += (c < NCLS) ? ex * h2[s * NCLS + c] : ex;
    }
    acc += __shfl_xor(acc, 8); acc += __shfl_xor(acc, 16); acc += __shfl_xor(acc, 32);
    float den = __shfl(acc, lane | 7) + 1e-16f;
    float v = acc / den + b2[c < NCLS ? c : 0];
    float vm = (c < NCLS) ? v : -INFINITY;
    vm = fmaxf(vm, __shfl_xor(vm, 1));
    vm = fmaxf(vm, __shfl_xor(vm, 2));
    vm = fmaxf(vm, __shfl_xor(vm, 4));
    float ev = (c < NCLS) ? __expf(v - vm) : 0.f;
    ev += __shfl_xor(ev, 1); ev += __shfl_xor(ev, 2); ev += __shfl_xor(ev, 4);
    float lse = vm + logf(ev);
    if (g == 0 && c < NCLS) out[n * NCLS + c] = v - lse;
}

extern "C" void kernel_launch(void* const* d_in, const int* in_sizes, int n_in,
                              void* d_out, int out_size, void* d_ws, size_t ws_size,
                              hipStream_t stream){
    const float* x    = (const float*)d_in[0];
    const int*   ei   = (const int*)  d_in[1];
    const float* W1   = (const float*)d_in[2];
    const float* a1s  = (const float*)d_in[3];
    const float* a1d  = (const float*)d_in[4];
    const float* b1   = (const float*)d_in[5];
    const float* W2   = (const float*)d_in[6];
    const float* a2s  = (const float*)d_in[7];
    const float* a2d  = (const float*)d_in[8];
    const float* b2   = (const float*)d_in[9];
    float* out = (float*)d_out;

    float* w = (float*)d_ws;
    unsigned short* h1b = (unsigned short*)w;  w += (size_t)N_NODES * C1 / 2;
    float*    als1 = w;              w += N_NODES * HEADS;
    float*    ald1 = w;              w += N_NODES * HEADS;
    float*    h2   = w;              w += N_NODES * NCLS;
    float*    als2 = w;              w += N_NODES;
    float*    ald2 = w;              w += N_NODES;
    unsigned short* wfh = (unsigned short*)w;  w += (16 * 4 * 64 * 8) / 2;
    unsigned short* wfl = (unsigned short*)w;  w += (16 * 4 * 64 * 8) / 2;
    int* deg     = (int*)w;          w += N_NODES;
    int* cur     = (int*)w;          w += N_NODES;
    int* ofs     = (int*)w;          w += N_NODES;
    int* bsum    = (int*)w;          w += 256;
    int* bbase   = (int*)w;          w += 256;
    int* csr_src = (int*)w;          w += ETOT;

    k_zero   <<<NBLK, 256, 0, stream>>>(deg);
    k_hist   <<<(E_EDGES + 255) / 256, 256, 0, stream>>>(ei, deg);
    k_bsum   <<<NBLK, 256, 0, stream>>>(deg, bsum);
    k_bscan  <<<1, 256, 0, stream>>>(bsum, bbase);
    k_apply  <<<NBLK, 256, 0, stream>>>(deg, bbase, ofs, cur, csr_src);
    k_scatter<<<(E_EDGES + 255) / 256, 256, 0, stream>>>(ei, ofs, cur, csr_src);
    k_wprep  <<<16, 256, 0, stream>>>(W1, wfh, wfl);
    k_gemm1  <<<(N_NODES + 63) / 64, 256, 0, stream>>>(x, wfh, wfl, a1s, a1d,
                                                       h1b, als1, ald1);
    k_agg1   <<<N_NODES / 4, 256, 0, stream>>>(csr_src, ofs, deg, als1, ald1, h1b,
                                               b1, W2, a2s, a2d, h2, als2, ald2);
    k_agg2   <<<N_NODES / 4, 256, 0, stream>>>(csr_src, ofs, deg, als2, ald2, h2, b2, out);
}